// Round 14
// baseline (163.451 us; speedup 1.0000x reference)
//
#include <hip/hip_runtime.h>

constexpr int Bn   = 4096;
constexpr int OBS  = 390;
constexpr int ACTN = 20;
constexpr int IN   = 410;   // OBS + ACTN
constexpr int KPAD = 448;   // IN padded to multiple of 64
constexpr int E    = 8;
constexpr int NT   = 10;
constexpr int H1   = 1024;
constexpr int H2   = 512;
constexpr int D    = 256;

typedef __bf16 bf16x8 __attribute__((ext_vector_type(8)));
typedef float  f32x4  __attribute__((ext_vector_type(4)));
typedef unsigned short u16x8 __attribute__((ext_vector_type(8)));

__device__ __forceinline__ unsigned short f2bf(float f) {
    unsigned int u = __float_as_uint(f);
    unsigned int r = u + 0x7fffu + ((u >> 16) & 1u);   // RNE
    return (unsigned short)(r >> 16);
}
__device__ __forceinline__ void gload16(void* lds_dst, const void* g_src) {
    __builtin_amdgcn_global_load_lds(
        (const __attribute__((address_space(1))) void*)g_src,
        (__attribute__((address_space(3))) void*)lds_dst,
        16, 0, 0);
}

// ---------------- prep_all: tc64 transposes + x-cast + qproj + bias concat, ONE launch ----------------
struct TD2 {
    const float* W;
    unsigned short* WT;
    int K, Kpad, N;
    long long gsW, gsO;
    int tilesN, perG, start;
};
struct TD2Arr { TD2 d[8]; };

constexpr int XCH    = KPAD / 8;            // 56 bf16x8 chunks per row
constexpr int PREPB  = (Bn * XCH) / 256;    // 896 blocks for x-cast

__global__ __launch_bounds__(256) void prep_all(
    TD2Arr da, int tcb,
    const float* __restrict__ sf, const float* __restrict__ ac,
    unsigned short* __restrict__ x,
    const float* __restrict__ kW2, const float* __restrict__ kb2,
    const float* __restrict__ emb, float* __restrict__ qp, float* __restrict__ qb,
    const float* __restrict__ kb1, const float* __restrict__ vb1,
    float* __restrict__ b1cat)
{
    __shared__ float tile[64][68];
    int bid = blockIdx.x;
    int t = threadIdx.x;

    if (bid < tcb) {
        int i = 0;
#pragma unroll
        for (int j = 1; j < 8; ++j) if (bid >= da.d[j].start) i = j;
        TD2 dd = da.d[i];
        int local = bid - dd.start;
        int g   = local / dd.perG;
        int rem = local - g * dd.perG;
        int kt  = rem / dd.tilesN;
        int nt  = rem - kt * dd.tilesN;
        const float* W = dd.W + (long long)g * dd.gsW;
        unsigned short* WT = dd.WT + (long long)g * dd.gsO;
        int k0 = kt * 64, n0 = nt * 64;
        {
            int kl  = t >> 4;
            int nl4 = (t & 15) * 4;
#pragma unroll
            for (int r = 0; r < 4; ++r) {
                int k = k0 + kl + r * 16;
                float4 v = make_float4(0.f, 0.f, 0.f, 0.f);
                if (k < dd.K) v = *(const float4*)(W + (long long)k * dd.N + n0 + nl4);
                *(float4*)&tile[kl + r * 16][nl4] = v;
            }
        }
        __syncthreads();
        int nl = t >> 2, kc = (t & 3) * 16;
        if (k0 + kc < dd.Kpad) {
            u16x8 o0, o1;
#pragma unroll
            for (int j = 0; j < 8; ++j) {
                o0[j] = f2bf(tile[kc + j][nl]);
                o1[j] = f2bf(tile[kc + 8 + j][nl]);
            }
            unsigned short* dst = WT + (long long)(n0 + nl) * dd.Kpad + k0 + kc;
            *(u16x8*)dst       = o0;
            *(u16x8*)(dst + 8) = o1;
        }
        return;
    }
    int bid2 = bid - tcb;
    if (bid2 < PREPB) {
        int cidx = bid2 * 256 + t;           // chunk index, 8 bf16 per chunk
        int b  = cidx / XCH;
        int cc = cidx - b * XCH;
        int k0 = cc * 8;
        u16x8 o;
        if (cc < 48) {                       // k0+7 <= 383 < OBS: pure state_feat
            const float* s = sf + (long long)b * OBS + k0;   // 8B-aligned
#pragma unroll
            for (int j = 0; j < 4; ++j) {
                float2 v = *(const float2*)(s + j * 2);
                o[j * 2]     = f2bf(v.x);
                o[j * 2 + 1] = f2bf(v.y);
            }
        } else {
#pragma unroll
            for (int j = 0; j < 8; ++j) {
                int k = k0 + j;
                float v = 0.f;
                if (k < OBS) v = sf[(long long)b * OBS + k];
                else if (k < IN) v = ac[b * ACTN + (k - OBS)];
                o[j] = f2bf(v);
            }
        }
        *(u16x8*)(x + (long long)b * KPAD + k0) = o;
        return;
    }
    if (bid2 < PREPB + 17) {
        int qbid = bid2 - PREPB;
        float* tq = &tile[0][0];   // [NT*D] = 2560 floats fits
        for (int i = t; i < NT * D; i += 256) tq[i] = tanhf(emb[i]);
        __syncthreads();
        if (qbid < 16) {
            int e = qbid >> 1;
            int h = (qbid & 1) * 256 + t;
            const float4* row = (const float4*)(kW2 + ((long long)e * H2 + h) * D);
            float acc[NT] = {};
            for (int d4 = 0; d4 < D / 4; ++d4) {
                float4 wv = row[d4];
#pragma unroll
                for (int tt = 0; tt < NT; ++tt)
                    acc[tt] += wv.x * tq[tt * D + d4 * 4] + wv.y * tq[tt * D + d4 * 4 + 1]
                             + wv.z * tq[tt * D + d4 * 4 + 2] + wv.w * tq[tt * D + d4 * 4 + 3];
            }
#pragma unroll
            for (int tt = 0; tt < NT; ++tt)
                qp[((long long)e * NT + tt) * H2 + h] = acc[tt];
        } else if (t < E * NT) {
            int e = t / NT, tt = t - e * NT;
            float s = 0.f;
            for (int d = 0; d < D; ++d) s += kb2[e * D + d] * tq[tt * D + d];
            qb[e * NT + tt] = s;
        }
        return;
    }
    int i = (bid2 - PREPB - 17) * 256 + t;   // < 2*E*H2 = 8192
    b1cat[i] = (i < E * H2) ? kb1[i] : vb1[i - E * H2];
}

// ---------------- 64x128 pipelined bf16 GEMM (R12 2-phase, BK=64) ----------------
// 4 waves side-by-side in N (each 64M x 32N, acc[4][2]). Grid (N/128, M/64, groups).
// OUTF: 0=f32 C, 1=bf16 C, 2=no C store, per-row tW3 dot -> qpart[row][bx*4+w]
template <int KT, int ACTF, int OUTF>
__global__ __launch_bounds__(256, 3) void gemm64x128(
    const unsigned short* __restrict__ A, const unsigned short* __restrict__ BT,
    const float* __restrict__ bias, void* __restrict__ Cout,
    int ldc, long long gsA, long long gsBT, long long gsBias, long long gsC,
    const float* __restrict__ tW3 = nullptr, float* __restrict__ qpart = nullptr)
{
    constexpr int NTK = KT / 64;
    static_assert(NTK >= 2, "KT must be >= 128");

    const int g = blockIdx.z;
    A    += (long long)g * gsA;
    BT   += (long long)g * gsBT;
    bias += (long long)g * gsBias;
    float*          Cf = (float*)Cout + (long long)g * gsC;
    unsigned short* Cb = (unsigned short*)Cout + (long long)g * gsC;

    __shared__ __align__(16) char smem[49152];
    const int tid = threadIdx.x;
    const int l  = tid & 63, lr = l & 15, lk = l >> 4;
    const int w  = tid >> 6;
    const int gm = blockIdx.y * 64, gn = blockIdx.x * 128;

    const int srow = tid >> 3;                    // 0..31
    const int cg   = (tid & 7) ^ (srow & 7);      // pre-swizzled global chunk
    const unsigned short* gA = A  + (long long)(gm + srow) * KT + cg * 8;
    const unsigned short* gB = BT + (long long)(gn + srow) * KT + cg * 8;
    const int wb = w * 1024;

    const int cs0 = ((0 | lk) ^ (lr & 7)) * 16;
    const int cs1 = ((4 | lk) ^ (lr & 7)) * 16;
    const int aRow = lr * 128;
    const int bRow = 8192 + (w * 32 + lr) * 128;

    f32x4 acc[4][2] = {};

    auto stA = [&](int c, int kt) {
#pragma unroll
        for (int j = 0; j < 2; ++j)
            gload16(smem + c * 24576 + j * 4096 + wb,
                    gA + (long long)(j * 32) * KT + kt * 64);
    };
    auto stB = [&](int c, int kt) {
#pragma unroll
        for (int j = 0; j < 4; ++j)
            gload16(smem + c * 24576 + 8192 + j * 4096 + wb,
                    gB + (long long)(j * 32) * KT + kt * 64);
    };

    // prologue: A(0)=2, B(0)=4, A(1)=2; vmcnt(2) retires tile0's 6, keeps A(1)
    stA(0, 0); stB(0, 0); stA(1, 1);
    asm volatile("s_waitcnt vmcnt(2)" ::: "memory");
    __builtin_amdgcn_s_barrier();
    __builtin_amdgcn_sched_barrier(0);

#pragma unroll
    for (int kt = 0; kt < NTK; ++kt) {
        const int c = kt & 1;
        const char* bufc = smem + c * 24576;
        bf16x8 a[4][2], b[1][2], b2[1][2];

        // ph0: read A-all + b(nf0); stage B(kt+1) -> buf c^1; 8 MFMA
#pragma unroll
        for (int m = 0; m < 4; ++m) {
            const char* base = bufc + aRow + m * 2048;
            a[m][0] = *(const bf16x8*)(base + cs0);
            a[m][1] = *(const bf16x8*)(base + cs1);
        }
        {
            const char* base = bufc + bRow;
            b[0][0] = *(const bf16x8*)(base + cs0);
            b[0][1] = *(const bf16x8*)(base + cs1);
        }
        if (kt + 1 < NTK) stB(c ^ 1, kt + 1);
        __builtin_amdgcn_s_setprio(1);
#pragma unroll
        for (int ks = 0; ks < 2; ++ks)
#pragma unroll
            for (int m = 0; m < 4; ++m)
                acc[m][0] = __builtin_amdgcn_mfma_f32_16x16x32_bf16(
                    a[m][ks], b[0][ks], acc[m][0], 0, 0, 0);
        __builtin_amdgcn_s_setprio(0);

        // ph1: read b(nf1); free buf c; stage A(kt+2) -> buf c; 8 MFMA
        {
            const char* base = bufc + bRow + 2048;
            b2[0][0] = *(const bf16x8*)(base + cs0);
            b2[0][1] = *(const bf16x8*)(base + cs1);
        }
        asm volatile("s_waitcnt lgkmcnt(0)" ::: "memory");
        __builtin_amdgcn_sched_barrier(0);
        if (kt + 2 < NTK) {
            __builtin_amdgcn_s_barrier();
            __builtin_amdgcn_sched_barrier(0);
            stA(c, kt + 2);
        }
        __builtin_amdgcn_s_setprio(1);
#pragma unroll
        for (int ks = 0; ks < 2; ++ks)
#pragma unroll
            for (int m = 0; m < 4; ++m)
                acc[m][1] = __builtin_amdgcn_mfma_f32_16x16x32_bf16(
                    a[m][ks], b2[0][ks], acc[m][1], 0, 0, 0);
        __builtin_amdgcn_s_setprio(0);

        // boundary: tile kt+1 (A=2,B=4) landed; A(kt+2)=2 in flight
        if (kt + 1 < NTK) {
            if (kt + 2 < NTK) { asm volatile("s_waitcnt vmcnt(2)" ::: "memory"); }
            else              { asm volatile("s_waitcnt vmcnt(0)" ::: "memory"); }
            __builtin_amdgcn_sched_barrier(0);
            __builtin_amdgcn_s_barrier();
            __builtin_amdgcn_sched_barrier(0);
        }
    }

    const int orow0 = gm + lk * 4;
    const int ocol0 = gn + w * 32 + lr;
    float bv[2];
#pragma unroll
    for (int nf = 0; nf < 2; ++nf) bv[nf] = bias[gn + w * 32 + lr + nf * 16];

    if (OUTF == 2) {
        float tw3v[2];
#pragma unroll
        for (int nf = 0; nf < 2; ++nf) tw3v[nf] = tW3[gn + w * 32 + lr + nf * 16];
#pragma unroll
        for (int mi = 0; mi < 4; ++mi)
#pragma unroll
            for (int r = 0; r < 4; ++r) {
                float part = 0.f;
#pragma unroll
                for (int nf = 0; nf < 2; ++nf) {
                    float v = acc[mi][nf][r] + bv[nf];
                    if (ACTF == 1) v = fmaxf(v, 0.f);
                    part += v * tw3v[nf];
                }
                part += __shfl_xor(part, 1);
                part += __shfl_xor(part, 2);
                part += __shfl_xor(part, 4);
                part += __shfl_xor(part, 8);
                if (lr == 0)
                    qpart[(orow0 + mi * 16 + r) * 8 + blockIdx.x * 4 + w] = part;
            }
    } else {
#pragma unroll
        for (int mi = 0; mi < 4; ++mi)
#pragma unroll
            for (int nf = 0; nf < 2; ++nf)
#pragma unroll
                for (int r = 0; r < 4; ++r) {
                    float v = acc[mi][nf][r] + bv[nf];
                    if (ACTF == 1) v = fmaxf(v, 0.f);
                    long long off = (long long)(orow0 + mi * 16 + r) * ldc + ocol0 + nf * 16;
                    if (OUTF == 0) Cf[off] = v;
                    else           Cb[off] = f2bf(v);
                }
    }
}

// ---------------- 256x128 8-wave pipelined bf16 GEMM (2-phase, BK=32, 2 blocks/CU) ----------------
// 8 waves (4M x 2N), wave tile 64x64, acc[4][4]=64 VGPR. LDS 48KB (A 16K + B 8K, dbuf).
// Swizzle f(r)=(r^(r>>2))&3 on 4 chunks (store via pre-swz source, read with same XOR).
// Per K-tile(32): ph0 {read A4+B2, stage B(kt+1)=1, 8 MFMA}; ph1 {read B2, lgkm0,
// barrier, stage A(kt+2)=2, 8 MFMA}; boundary vmcnt(2) (A(kt+2) in flight).
// SC=1: groups g<E score-only; qp slice + task_id LDS-staged post-K-loop.
template <int KTOT, int ACTF, int OUTF, int SC>
__global__ __launch_bounds__(512, 4) void gemm256(
    const unsigned short* __restrict__ A, const unsigned short* __restrict__ BT,
    const float* __restrict__ bias, void* __restrict__ Cout,
    int ldc, long long gsA, long long gsBT, long long gsBias, long long gsC,
    const int* __restrict__ task_id, const float* __restrict__ qp,
    float* __restrict__ spart)
{
    constexpr int NTK = KTOT / 32;
    static_assert(NTK >= 2, "KTOT must be >= 64");

    const int g = blockIdx.z;
    A    += (long long)g * gsA;
    BT   += (long long)g * gsBT;
    bias += (long long)g * gsBias;
    float*          Cf = (float*)Cout + (long long)g * gsC;
    unsigned short* Cb = (unsigned short*)Cout + (long long)g * gsC;

    __shared__ __align__(16) char smem[49152];

    const int tid = threadIdx.x;
    const int l  = tid & 63;
    const int lr = l & 15, lk = l >> 4;
    const int w  = tid >> 6;
    const int wr = w >> 1, wc = w & 1;            // 4M x 2N wave grid
    const int gm = blockIdx.y * 256, gn = blockIdx.x * 128;

    const int srow = tid >> 2;                    // 0..127
    const int scg  = (tid & 3) ^ ((srow ^ (srow >> 2)) & 3);   // pre-swizzled chunk
    const unsigned short* gA = A  + (long long)(gm + srow) * KTOT + scg * 8;
    const unsigned short* gB = BT + (long long)(gn + srow) * KTOT + scg * 8;
    const int wb = w * 1024;

    const int fsw = (lr ^ (lr >> 2)) & 3;         // row-base-invariant read swizzle
    const int csA = (lk ^ fsw) * 16;
    const int aRowB = (wr * 64 + lr) * 64;        // + mi*1024
    const int bRowB = 16384 + (wc * 64 + lr) * 64;// + ni*1024

    f32x4 acc[4][4] = {};

    auto stA = [&](int c, int kt) {               // 2 gloads: rows srow, srow+128
#pragma unroll
        for (int j = 0; j < 2; ++j)
            gload16(smem + c * 24576 + j * 8192 + wb,
                    gA + (long long)(j * 128) * KTOT + kt * 32);
    };
    auto stB = [&](int c, int kt) {               // 1 gload: rows srow (0..127)
        gload16(smem + c * 24576 + 16384 + wb,
                gB + kt * 32);
    };

    // prologue: A(0)=2, B(0)=1, A(1)=2; vmcnt(2) retires tile0's 3, keeps A(1)
    stA(0, 0); stB(0, 0); stA(1, 1);
    asm volatile("s_waitcnt vmcnt(2)" ::: "memory");
    __builtin_amdgcn_s_barrier();
    __builtin_amdgcn_sched_barrier(0);

#pragma unroll 2
    for (int kt = 0; kt < NTK; ++kt) {
        const int c = kt & 1;
        const char* bufc = smem + c * 24576;
        bf16x8 a[4], b[2], b2[2];

        // ph0: read A-all + B n0/n1; stage B(kt+1) -> buf c^1; 8 MFMA
#pragma unroll
        for (int mi = 0; mi < 4; ++mi)
            a[mi] = *(const bf16x8*)(bufc + aRowB + mi * 1024 + csA);
#pragma unroll
        for (int ni = 0; ni < 2; ++ni)
            b[ni] = *(const bf16x8*)(bufc + bRowB + ni * 1024 + csA);
        if (kt + 1 < NTK) stB(c ^ 1, kt + 1);
        __builtin_amdgcn_s_setprio(1);
#pragma unroll
        for (int mi = 0; mi < 4; ++mi)
#pragma unroll
            for (int ni = 0; ni < 2; ++ni)
                acc[mi][ni] = __builtin_amdgcn_mfma_f32_16x16x32_bf16(
                    a[mi], b[ni], acc[mi][ni], 0, 0, 0);
        __builtin_amdgcn_s_setprio(0);

        // ph1: read B n2/n3; drain; barrier; stage A(kt+2) -> buf c; 8 MFMA
#pragma unroll
        for (int ni = 0; ni < 2; ++ni)
            b2[ni] = *(const bf16x8*)(bufc + bRowB + (2 + ni) * 1024 + csA);
        asm volatile("s_waitcnt lgkmcnt(0)" ::: "memory");
        __builtin_amdgcn_sched_barrier(0);
        if (kt + 2 < NTK) {
            __builtin_amdgcn_s_barrier();
            __builtin_amdgcn_sched_barrier(0);
            stA(c, kt + 2);
        }
        __builtin_amdgcn_s_setprio(1);
#pragma unroll
        for (int mi = 0; mi < 4; ++mi)
#pragma unroll
            for (int ni = 0; ni < 2; ++ni)
                acc[mi][2 + ni] = __builtin_amdgcn_mfma_f32_16x16x32_bf16(
                    a[mi], b2[ni], acc[mi][2 + ni], 0, 0, 0);
        __builtin_amdgcn_s_setprio(0);

        // boundary: tile kt+1 (A=2,B=1) landed; A(kt+2)=2 in flight
        if (kt + 1 < NTK) {
            if (kt + 2 < NTK) { asm volatile("s_waitcnt vmcnt(2)" ::: "memory"); }
            else              { asm volatile("s_waitcnt vmcnt(0)" ::: "memory"); }
            __builtin_amdgcn_sched_barrier(0);
            __builtin_amdgcn_s_barrier();
            __builtin_amdgcn_sched_barrier(0);
        }
    }

    const int orow0 = gm + wr * 64 + lk * 4;
    const int ocol0 = gn + wc * 64 + lr;
    float bv[4];
#pragma unroll
    for (int ni = 0; ni < 4; ++ni) bv[ni] = bias[gn + wc * 64 + lr + ni * 16];

    if (SC && g < E) {
        __syncthreads();                       // all waves past their lgkm0; LDS free
        float* qpl  = (float*)smem;            // [NT][128]
        int*   tidl = (int*)(smem + NT * 128 * 4);
        for (int i = tid; i < NT * 128; i += 512) {
            int tt = i >> 7, cc = i & 127;
            qpl[i] = qp[((long long)(g * NT + tt)) * H2 + gn + cc];
        }
        if (tid < 256) tidl[tid] = task_id[gm + tid];
        __syncthreads();

        const int rbase = wr * 64 + lk * 4;
        const int cbase = wc * 64 + lr;
#pragma unroll
        for (int mi = 0; mi < 4; ++mi) {
#pragma unroll
            for (int r = 0; r < 4; ++r) {
                int trow = tidl[rbase + mi * 16 + r];
                float rp = 0.f;
#pragma unroll
                for (int ni = 0; ni < 4; ++ni) {
                    float v = acc[mi][ni][r] + bv[ni];
                    v = fmaxf(v, 0.f);
                    rp += v * qpl[trow * 128 + cbase + ni * 16];
                }
                rp += __shfl_xor(rp, 1);
                rp += __shfl_xor(rp, 2);
                rp += __shfl_xor(rp, 4);
                rp += __shfl_xor(rp, 8);
                if (lr == 0)
                    spart[(((long long)g * Bn + orow0 + mi * 16 + r) << 3)
                          + (blockIdx.x << 1) + wc] = rp;
            }
        }
    } else {
#pragma unroll
        for (int mi = 0; mi < 4; ++mi)
#pragma unroll
            for (int ni = 0; ni < 4; ++ni)
#pragma unroll
                for (int r = 0; r < 4; ++r) {
                    float v = acc[mi][ni][r] + bv[ni];
                    if (ACTF == 1) v = fmaxf(v, 0.f);
                    long long off = (long long)(orow0 + mi * 16 + r) * ldc + ocol0 + ni * 16;
                    if (OUTF == 0) Cf[off] = v;
                    else           Cb[off] = f2bf(v);
                }
    }
}

// ---------------- attn: scores from spart partials, softmax, weighted vals sum, loss ----------------
__global__ __launch_bounds__(256) void attn_kernel(
    const float* __restrict__ spart, const float* __restrict__ qb,
    const int* __restrict__ task_id, const unsigned short* __restrict__ vals,
    unsigned short* __restrict__ tower_in, float* __restrict__ loss_partial)
{
    int wv   = threadIdx.x >> 6;
    int lane = threadIdx.x & 63;
    int b    = blockIdx.x * 4 + wv;
    int t    = task_id[b];

    float s[E];
#pragma unroll
    for (int e = 0; e < E; ++e) {
        const float4* sp = (const float4*)(spart + (((long long)e * Bn + b) << 3));
        float4 p0 = sp[0], p1 = sp[1];
        s[e] = p0.x + p0.y + p0.z + p0.w + p1.x + p1.y + p1.z + p1.w + qb[e * NT + t];
    }

    float m = s[0];
#pragma unroll
    for (int e = 1; e < E; ++e) m = fmaxf(m, s[e]);
    float wgt[E];
    float sum = 0.f;
#pragma unroll
    for (int e = 0; e < E; ++e) { wgt[e] = expf(s[e] - m); sum += wgt[e]; }
    float inv = 1.f / sum;

    int d0 = lane * 4;
    float4 acc = make_float4(0.f, 0.f, 0.f, 0.f);
    float lb = 0.f;
#pragma unroll
    for (int e = 0; e < E; ++e) {
        float we = wgt[e] * inv;
        uint2 vv = *(const uint2*)&vals[((long long)e * Bn + b) * D + d0];
        acc.x += we * __uint_as_float(vv.x << 16);
        acc.y += we * __uint_as_float(vv.x & 0xffff0000u);
        acc.z += we * __uint_as_float(vv.y << 16);
        acc.w += we * __uint_as_float(vv.y & 0xffff0000u);
        lb += fminf(fmaxf(logf(we + 1e-10f), -6.f), 0.f);
    }
    ushort4 o;
    o.x = f2bf(acc.x); o.y = f2bf(acc.y); o.z = f2bf(acc.z); o.w = f2bf(acc.w);
    *(ushort4*)&tower_in[(long long)b * D + d0] = o;

    __shared__ float sm[4];
    if (lane == 0) sm[wv] = lb;
    __syncthreads();
    if (threadIdx.x == 0)
        loss_partial[blockIdx.x] = sm[0] + sm[1] + sm[2] + sm[3];
}

// ---------------- qfin: out[b] = sum(qpart[b][0..7])+tb3 ; last block: loss ----------------
__global__ __launch_bounds__(256) void qfin_kernel(
    const float* __restrict__ qpart, const float* __restrict__ tb3,
    float* __restrict__ out, const float* __restrict__ lossp)
{
    if (blockIdx.x == Bn / 256) {
        float s = 0.f;
        for (int i = threadIdx.x; i < Bn / 4; i += 256) s += lossp[i];
#pragma unroll
        for (int off = 32; off > 0; off >>= 1) s += __shfl_xor(s, off, 64);
        __shared__ float sm[4];
        if ((threadIdx.x & 63) == 0) sm[threadIdx.x >> 6] = s;
        __syncthreads();
        if (threadIdx.x == 0) out[Bn] = (-0.3f / Bn) * (sm[0] + sm[1] + sm[2] + sm[3]);
        return;
    }
    int b = blockIdx.x * 256 + threadIdx.x;
    const float4* qq = (const float4*)&qpart[b * 8];
    float4 a0 = qq[0], a1 = qq[1];
    out[b] = a0.x + a0.y + a0.z + a0.w + a1.x + a1.y + a1.z + a1.w + tb3[0];
}

extern "C" void kernel_launch(void* const* d_in, const int* in_sizes, int n_in,
                              void* d_out, int out_size, void* d_ws, size_t ws_size,
                              hipStream_t stream) {
    const float* state_feat = (const float*)d_in[0];
    const float* act        = (const float*)d_in[1];
    const int*   task_id    = (const int*)d_in[2];
    const float* rep_W1 = (const float*)d_in[3];
    const float* rep_b1 = (const float*)d_in[4];
    const float* rep_W2 = (const float*)d_in[5];
    const float* rep_b2 = (const float*)d_in[6];
    const float* emb    = (const float*)d_in[7];
    const float* kW1 = (const float*)d_in[8];
    const float* kb1 = (const float*)d_in[9];
    const float* kW2 = (const float*)d_in[10];
    const float* kb2 = (const float*)d_in[11];
    const float* vW1 = (const float*)d_in[12];
    const float* vb1 = (const float*)d_in[13];
    const float* vW2 = (const float*)d_in[14];
    const float* vb2 = (const float*)d_in[15];
    const float* tW1 = (const float*)d_in[16];
    const float* tb1 = (const float*)d_in[17];
    const float* tW2 = (const float*)d_in[18];
    const float* tb2 = (const float*)d_in[19];
    const float* tW3 = (const float*)d_in[20];
    const float* tb3 = (const float*)d_in[21];
    float* out = (float*)d_out;

    // ---- workspace (~92 MB) ----
    char* p = (char*)d_ws;
    auto alloc = [&](size_t bytes) {
        char* r = p;
        p += (bytes + 255) & ~(size_t)255;
        return r;
    };
    unsigned short* x      = (unsigned short*)alloc((size_t)Bn * KPAD * 2);
    unsigned short* repW1T = (unsigned short*)alloc((size_t)H1 * KPAD * 2);
    unsigned short* repW2T = (unsigned short*)alloc((size_t)H1 * H1 * 2);
    unsigned short* w1T    = (unsigned short*)alloc((size_t)2 * E * H2 * H1 * 2);  // K then V
    unsigned short* w2T    = (unsigned short*)alloc((size_t)E * D * H2 * 2);       // V only
    unsigned short* tW1T   = (unsigned short*)alloc((size_t)D * D * 2);
    unsigned short* tW2T   = (unsigned short*)alloc((size_t)D * D * 2);
    float*          b1cat  = (float*)alloc((size_t)2 * E * H2 * 4);
    float*          qp     = (float*)alloc((size_t)E * NT * H2 * 4);
    float*          qb     = (float*)alloc((size_t)E * NT * 4);
    char*           h1zone = alloc((size_t)Bn * H1 * 2);
    unsigned short* rep    = (unsigned short*)alloc((size_t)Bn * H1 * 2);
    unsigned short* hkv    = (unsigned short*)alloc((size_t)2 * E * Bn * H2 * 2);
    unsigned short* vals   = (unsigned short*)alloc((size_t)E * Bn * D * 2);
    float*          spart  = (float*)alloc((size_t)E * Bn * 8 * 4);
    float*          qpart  = (float*)alloc((size_t)Bn * 8 * 4);
    float*          lossp  = (float*)alloc((size_t)(Bn / 4) * 4);

    unsigned short* h1       = (unsigned short*)h1zone;
    unsigned short* tower_in = (unsigned short*)h1zone;
    unsigned short* t1       = (unsigned short*)(h1zone + (size_t)Bn * D * 2);
    unsigned short* hv = hkv + (size_t)E * Bn * H2;

    // ---- 1. prep_all: transposes + x-cast + qproj + bias concat (1 launch) ----
    TD2Arr da;
    int startAcc = 0;
    auto setd = [&](int i, const float* W, unsigned short* WT, int K, int Kpad, int N,
                    long long gsW, long long gsO, int groups) {
        TD2& dd = da.d[i];
        dd.W = W; dd.WT = WT; dd.K = K; dd.Kpad = Kpad; dd.N = N;
        dd.gsW = gsW; dd.gsO = gsO;
        dd.tilesN = N / 64;
        dd.perG = ((Kpad + 63) / 64) * dd.tilesN;
        dd.start = startAcc;
        startAcc += dd.perG * groups;
    };
    setd(0, rep_W1, repW1T, IN, KPAD, H1, 0, 0, 1);
    setd(1, rep_W2, repW2T, H1, H1, H1, 0, 0, 1);
    setd(2, kW1, w1T,                       H1, H1, H2, (long long)H1 * H2, (long long)H2 * H1, E);
    setd(3, vW1, w1T + (size_t)E * H2 * H1, H1, H1, H2, (long long)H1 * H2, (long long)H2 * H1, E);
    setd(4, vW2, w2T,                       H2, H2, D, (long long)H2 * D, (long long)D * H2, E);
    setd(5, tW1, tW1T, D, D, D, 0, 0, 1);
    setd(6, tW2, tW2T, D, D, D, 0, 0, 1);
    da.d[7] = da.d[6];
    da.d[7].start = 0x7fffffff;
    int totalBlocks = startAcc + PREPB + 17 + 32;
    prep_all<<<totalBlocks, 256, 0, stream>>>(
        da, startAcc, state_feat, act, x, kW2, kb2, emb, qp, qb, kb1, vb1, b1cat);

    // ---- 2. rep MLP (64x128-tile pipelined) ----
    gemm64x128<KPAD, 1, 1><<<dim3(H1 / 128, Bn / 64, 1), 256, 0, stream>>>(
        x, repW1T, rep_b1, h1, H1, 0, 0, 0, 0);
    gemm64x128<H1, 0, 1><<<dim3(H1 / 128, Bn / 64, 1), 256, 0, stream>>>(
        h1, repW2T, rep_b2, rep, H1, 0, 0, 0, 0);

    // ---- 3. expert L1 K+V fused (256x128 BK32, 2 blocks/CU, scores in epilogue); L2 V-only ----
    gemm256<H1, 1, 1, 1><<<dim3(H2 / 128, Bn / 256, 2 * E), 512, 0, stream>>>(
        rep, w1T, b1cat, hkv, H2,
        0, (long long)H2 * H1, H2, (long long)Bn * H2,
        task_id, qp, spart);
    gemm64x128<H2, 0, 1><<<dim3(D / 128, Bn / 64, E), 256, 0, stream>>>(
        hv, w2T, vb2, vals, D,
        (long long)Bn * H2, (long long)D * H2, D, (long long)Bn * D);

    // ---- 4. attention (scores from spart partials) ----
    attn_kernel<<<Bn / 4, 256, 0, stream>>>(
        spart, qb, task_id, vals, tower_in, lossp);

    // ---- 5. tower (64x128-tile; tower2 fuses the tW3 dot) ----
    gemm64x128<D, 1, 1><<<dim3(D / 128, Bn / 64, 1), 256, 0, stream>>>(
        tower_in, tW1T, tb1, t1, D, 0, 0, 0, 0);
    gemm64x128<D, 1, 2><<<dim3(D / 128, Bn / 64, 1), 256, 0, stream>>>(
        t1, tW2T, tb2, nullptr, D, 0, 0, 0, 0, tW3, qpart);

    // ---- 6. q + loss ----
    qfin_kernel<<<Bn / 256 + 1, 256, 0, stream>>>(qpart, tb3, out, lossp);
}

// Round 15
// 155.960 us; speedup vs baseline: 1.0480x; 1.0480x over previous
//
#include <hip/hip_runtime.h>

constexpr int Bn   = 4096;
constexpr int OBS  = 390;
constexpr int ACTN = 20;
constexpr int IN   = 410;   // OBS + ACTN
constexpr int KPAD = 448;   // IN padded to multiple of 64
constexpr int E    = 8;
constexpr int NT   = 10;
constexpr int H1   = 1024;
constexpr int H2   = 512;
constexpr int D    = 256;

typedef __bf16 bf16x8 __attribute__((ext_vector_type(8)));
typedef float  f32x4  __attribute__((ext_vector_type(4)));
typedef unsigned short u16x8 __attribute__((ext_vector_type(8)));

__device__ __forceinline__ unsigned short f2bf(float f) {
    unsigned int u = __float_as_uint(f);
    unsigned int r = u + 0x7fffu + ((u >> 16) & 1u);   // RNE
    return (unsigned short)(r >> 16);
}
__device__ __forceinline__ void gload16(void* lds_dst, const void* g_src) {
    __builtin_amdgcn_global_load_lds(
        (const __attribute__((address_space(1))) void*)g_src,
        (__attribute__((address_space(3))) void*)lds_dst,
        16, 0, 0);
}

// ---------------- prep_all: tc64 transposes + x-cast + qproj + bias concat, ONE launch ----------------
struct TD2 {
    const float* W;
    unsigned short* WT;
    int K, Kpad, N;
    long long gsW, gsO;
    int tilesN, perG, start;
};
struct TD2Arr { TD2 d[8]; };

constexpr int XCH    = KPAD / 8;            // 56 bf16x8 chunks per row
constexpr int PREPB  = (Bn * XCH) / 256;    // 896 blocks for x-cast

__global__ __launch_bounds__(256) void prep_all(
    TD2Arr da, int tcb,
    const float* __restrict__ sf, const float* __restrict__ ac,
    unsigned short* __restrict__ x,
    const float* __restrict__ kW2, const float* __restrict__ kb2,
    const float* __restrict__ emb, float* __restrict__ qp, float* __restrict__ qb,
    const float* __restrict__ kb1, const float* __restrict__ vb1,
    float* __restrict__ b1cat)
{
    __shared__ float tile[64][68];
    int bid = blockIdx.x;
    int t = threadIdx.x;

    if (bid < tcb) {
        int i = 0;
#pragma unroll
        for (int j = 1; j < 8; ++j) if (bid >= da.d[j].start) i = j;
        TD2 dd = da.d[i];
        int local = bid - dd.start;
        int g   = local / dd.perG;
        int rem = local - g * dd.perG;
        int kt  = rem / dd.tilesN;
        int nt  = rem - kt * dd.tilesN;
        const float* W = dd.W + (long long)g * dd.gsW;
        unsigned short* WT = dd.WT + (long long)g * dd.gsO;
        int k0 = kt * 64, n0 = nt * 64;
        {
            int kl  = t >> 4;
            int nl4 = (t & 15) * 4;
#pragma unroll
            for (int r = 0; r < 4; ++r) {
                int k = k0 + kl + r * 16;
                float4 v = make_float4(0.f, 0.f, 0.f, 0.f);
                if (k < dd.K) v = *(const float4*)(W + (long long)k * dd.N + n0 + nl4);
                *(float4*)&tile[kl + r * 16][nl4] = v;
            }
        }
        __syncthreads();
        int nl = t >> 2, kc = (t & 3) * 16;
        if (k0 + kc < dd.Kpad) {
            u16x8 o0, o1;
#pragma unroll
            for (int j = 0; j < 8; ++j) {
                o0[j] = f2bf(tile[kc + j][nl]);
                o1[j] = f2bf(tile[kc + 8 + j][nl]);
            }
            unsigned short* dst = WT + (long long)(n0 + nl) * dd.Kpad + k0 + kc;
            *(u16x8*)dst       = o0;
            *(u16x8*)(dst + 8) = o1;
        }
        return;
    }
    int bid2 = bid - tcb;
    if (bid2 < PREPB) {
        int cidx = bid2 * 256 + t;           // chunk index, 8 bf16 per chunk
        int b  = cidx / XCH;
        int cc = cidx - b * XCH;
        int k0 = cc * 8;
        u16x8 o;
        if (cc < 48) {                       // k0+7 <= 383 < OBS: pure state_feat
            const float* s = sf + (long long)b * OBS + k0;   // 8B-aligned
#pragma unroll
            for (int j = 0; j < 4; ++j) {
                float2 v = *(const float2*)(s + j * 2);
                o[j * 2]     = f2bf(v.x);
                o[j * 2 + 1] = f2bf(v.y);
            }
        } else {
#pragma unroll
            for (int j = 0; j < 8; ++j) {
                int k = k0 + j;
                float v = 0.f;
                if (k < OBS) v = sf[(long long)b * OBS + k];
                else if (k < IN) v = ac[b * ACTN + (k - OBS)];
                o[j] = f2bf(v);
            }
        }
        *(u16x8*)(x + (long long)b * KPAD + k0) = o;
        return;
    }
    if (bid2 < PREPB + 17) {
        int qbid = bid2 - PREPB;
        float* tq = &tile[0][0];   // [NT*D] = 2560 floats fits
        for (int i = t; i < NT * D; i += 256) tq[i] = tanhf(emb[i]);
        __syncthreads();
        if (qbid < 16) {
            int e = qbid >> 1;
            int h = (qbid & 1) * 256 + t;
            const float4* row = (const float4*)(kW2 + ((long long)e * H2 + h) * D);
            float acc[NT] = {};
            for (int d4 = 0; d4 < D / 4; ++d4) {
                float4 wv = row[d4];
#pragma unroll
                for (int tt = 0; tt < NT; ++tt)
                    acc[tt] += wv.x * tq[tt * D + d4 * 4] + wv.y * tq[tt * D + d4 * 4 + 1]
                             + wv.z * tq[tt * D + d4 * 4 + 2] + wv.w * tq[tt * D + d4 * 4 + 3];
            }
#pragma unroll
            for (int tt = 0; tt < NT; ++tt)
                qp[((long long)e * NT + tt) * H2 + h] = acc[tt];
        } else if (t < E * NT) {
            int e = t / NT, tt = t - e * NT;
            float s = 0.f;
            for (int d = 0; d < D; ++d) s += kb2[e * D + d] * tq[tt * D + d];
            qb[e * NT + tt] = s;
        }
        return;
    }
    int i = (bid2 - PREPB - 17) * 256 + t;   // < 2*E*H2 = 8192
    b1cat[i] = (i < E * H2) ? kb1[i] : vb1[i - E * H2];
}

// ---------------- 64x128 pipelined bf16 GEMM (R12 2-phase, BK=64) ----------------
// 4 waves side-by-side in N (each 64M x 32N, acc[4][2]). Grid (N/128, M/64, groups).
// OUTF: 0=f32 C, 1=bf16 C, 2=no C store, per-row tW3 dot -> qpart[row][bx*4+w]
template <int KT, int ACTF, int OUTF>
__global__ __launch_bounds__(256, 3) void gemm64x128(
    const unsigned short* __restrict__ A, const unsigned short* __restrict__ BT,
    const float* __restrict__ bias, void* __restrict__ Cout,
    int ldc, long long gsA, long long gsBT, long long gsBias, long long gsC,
    const float* __restrict__ tW3 = nullptr, float* __restrict__ qpart = nullptr)
{
    constexpr int NTK = KT / 64;
    static_assert(NTK >= 2, "KT must be >= 128");

    const int g = blockIdx.z;
    A    += (long long)g * gsA;
    BT   += (long long)g * gsBT;
    bias += (long long)g * gsBias;
    float*          Cf = (float*)Cout + (long long)g * gsC;
    unsigned short* Cb = (unsigned short*)Cout + (long long)g * gsC;

    __shared__ __align__(16) char smem[49152];
    const int tid = threadIdx.x;
    const int l  = tid & 63, lr = l & 15, lk = l >> 4;
    const int w  = tid >> 6;
    const int gm = blockIdx.y * 64, gn = blockIdx.x * 128;

    const int srow = tid >> 3;                    // 0..31
    const int cg   = (tid & 7) ^ (srow & 7);      // pre-swizzled global chunk
    const unsigned short* gA = A  + (long long)(gm + srow) * KT + cg * 8;
    const unsigned short* gB = BT + (long long)(gn + srow) * KT + cg * 8;
    const int wb = w * 1024;

    const int cs0 = ((0 | lk) ^ (lr & 7)) * 16;
    const int cs1 = ((4 | lk) ^ (lr & 7)) * 16;
    const int aRow = lr * 128;
    const int bRow = 8192 + (w * 32 + lr) * 128;

    f32x4 acc[4][2] = {};

    auto stA = [&](int c, int kt) {
#pragma unroll
        for (int j = 0; j < 2; ++j)
            gload16(smem + c * 24576 + j * 4096 + wb,
                    gA + (long long)(j * 32) * KT + kt * 64);
    };
    auto stB = [&](int c, int kt) {
#pragma unroll
        for (int j = 0; j < 4; ++j)
            gload16(smem + c * 24576 + 8192 + j * 4096 + wb,
                    gB + (long long)(j * 32) * KT + kt * 64);
    };

    // prologue: A(0)=2, B(0)=4, A(1)=2; vmcnt(2) retires tile0's 6, keeps A(1)
    stA(0, 0); stB(0, 0); stA(1, 1);
    asm volatile("s_waitcnt vmcnt(2)" ::: "memory");
    __builtin_amdgcn_s_barrier();
    __builtin_amdgcn_sched_barrier(0);

#pragma unroll
    for (int kt = 0; kt < NTK; ++kt) {
        const int c = kt & 1;
        const char* bufc = smem + c * 24576;
        bf16x8 a[4][2], b[1][2], b2[1][2];

        // ph0: read A-all + b(nf0); stage B(kt+1) -> buf c^1; 8 MFMA
#pragma unroll
        for (int m = 0; m < 4; ++m) {
            const char* base = bufc + aRow + m * 2048;
            a[m][0] = *(const bf16x8*)(base + cs0);
            a[m][1] = *(const bf16x8*)(base + cs1);
        }
        {
            const char* base = bufc + bRow;
            b[0][0] = *(const bf16x8*)(base + cs0);
            b[0][1] = *(const bf16x8*)(base + cs1);
        }
        if (kt + 1 < NTK) stB(c ^ 1, kt + 1);
        __builtin_amdgcn_s_setprio(1);
#pragma unroll
        for (int ks = 0; ks < 2; ++ks)
#pragma unroll
            for (int m = 0; m < 4; ++m)
                acc[m][0] = __builtin_amdgcn_mfma_f32_16x16x32_bf16(
                    a[m][ks], b[0][ks], acc[m][0], 0, 0, 0);
        __builtin_amdgcn_s_setprio(0);

        // ph1: read b(nf1); free buf c; stage A(kt+2) -> buf c; 8 MFMA
        {
            const char* base = bufc + bRow + 2048;
            b2[0][0] = *(const bf16x8*)(base + cs0);
            b2[0][1] = *(const bf16x8*)(base + cs1);
        }
        asm volatile("s_waitcnt lgkmcnt(0)" ::: "memory");
        __builtin_amdgcn_sched_barrier(0);
        if (kt + 2 < NTK) {
            __builtin_amdgcn_s_barrier();
            __builtin_amdgcn_sched_barrier(0);
            stA(c, kt + 2);
        }
        __builtin_amdgcn_s_setprio(1);
#pragma unroll
        for (int ks = 0; ks < 2; ++ks)
#pragma unroll
            for (int m = 0; m < 4; ++m)
                acc[m][1] = __builtin_amdgcn_mfma_f32_16x16x32_bf16(
                    a[m][ks], b2[0][ks], acc[m][1], 0, 0, 0);
        __builtin_amdgcn_s_setprio(0);

        // boundary: tile kt+1 (A=2,B=4) landed; A(kt+2)=2 in flight
        if (kt + 1 < NTK) {
            if (kt + 2 < NTK) { asm volatile("s_waitcnt vmcnt(2)" ::: "memory"); }
            else              { asm volatile("s_waitcnt vmcnt(0)" ::: "memory"); }
            __builtin_amdgcn_sched_barrier(0);
            __builtin_amdgcn_s_barrier();
            __builtin_amdgcn_sched_barrier(0);
        }
    }

    const int orow0 = gm + lk * 4;
    const int ocol0 = gn + w * 32 + lr;
    float bv[2];
#pragma unroll
    for (int nf = 0; nf < 2; ++nf) bv[nf] = bias[gn + w * 32 + lr + nf * 16];

    if (OUTF == 2) {
        float tw3v[2];
#pragma unroll
        for (int nf = 0; nf < 2; ++nf) tw3v[nf] = tW3[gn + w * 32 + lr + nf * 16];
#pragma unroll
        for (int mi = 0; mi < 4; ++mi)
#pragma unroll
            for (int r = 0; r < 4; ++r) {
                float part = 0.f;
#pragma unroll
                for (int nf = 0; nf < 2; ++nf) {
                    float v = acc[mi][nf][r] + bv[nf];
                    if (ACTF == 1) v = fmaxf(v, 0.f);
                    part += v * tw3v[nf];
                }
                part += __shfl_xor(part, 1);
                part += __shfl_xor(part, 2);
                part += __shfl_xor(part, 4);
                part += __shfl_xor(part, 8);
                if (lr == 0)
                    qpart[(orow0 + mi * 16 + r) * 8 + blockIdx.x * 4 + w] = part;
            }
    } else {
#pragma unroll
        for (int mi = 0; mi < 4; ++mi)
#pragma unroll
            for (int nf = 0; nf < 2; ++nf)
#pragma unroll
                for (int r = 0; r < 4; ++r) {
                    float v = acc[mi][nf][r] + bv[nf];
                    if (ACTF == 1) v = fmaxf(v, 0.f);
                    long long off = (long long)(orow0 + mi * 16 + r) * ldc + ocol0 + nf * 16;
                    if (OUTF == 0) Cf[off] = v;
                    else           Cb[off] = f2bf(v);
                }
    }
}

// ---------------- 256x256 8-wave pipelined bf16 GEMM (R12-proven 2-phase schedule) ----------------
// SC=1: groups g<E score-only; qp slice + task_id staged into the idle LDS buffer
// DURING the last K-tile (buffer c^1 proven drained by the preceding boundary).
template <int KTOT, int ACTF, int OUTF, int SC>
__global__ __launch_bounds__(512, 2) void gemm256(
    const unsigned short* __restrict__ A, const unsigned short* __restrict__ BT,
    const float* __restrict__ bias, void* __restrict__ Cout,
    int ldc, long long gsA, long long gsBT, long long gsBias, long long gsC,
    const int* __restrict__ task_id, const float* __restrict__ qp,
    float* __restrict__ spart)
{
    constexpr int NT_ = KTOT / 64;
    static_assert(NT_ >= 4 && (NT_ % 2) == 0, "KTOT must be multiple of 128");
    constexpr int QBUF = (((NT_ - 1) & 1) ^ 1) * 65536;   // idle buffer during last tile

    const int g = blockIdx.z;
    A    += (long long)g * gsA;
    BT   += (long long)g * gsBT;
    bias += (long long)g * gsBias;
    float*          Cf = (float*)Cout + (long long)g * gsC;
    unsigned short* Cb = (unsigned short*)Cout + (long long)g * gsC;

    __shared__ __align__(16) char smem[131072];

    const int tid = threadIdx.x;
    const int l  = tid & 63;
    const int lr = l & 15, lk = l >> 4;
    const int w  = tid >> 6;
    const int wr = w >> 2, wc = w & 3;
    const int gm = blockIdx.y * 256, gn = blockIdx.x * 256;

    const int srow = tid >> 3;
    const int cg   = (tid & 7) ^ (srow & 7);
    const unsigned short* gA = A  + (long long)(gm + srow) * KTOT + cg * 8;
    const unsigned short* gB = BT + (long long)(gn + srow) * KTOT + cg * 8;
    const int wbase = (tid & ~63) * 16;

    const int cs0 = ((0 | lk) ^ (lr & 7)) * 16;
    const int cs1 = ((4 | lk) ^ (lr & 7)) * 16;
    const int aRow = wr * 16384 + lr * 128;
    const int bRow = 32768 + (wc >> 1) * 16384 + ((wc & 1) * 64 + lr) * 128;

    f32x4 acc[8][4] = {};

    auto stA = [&](int c, int s, int kt) {
        const unsigned short* src = gA + (long long)(s * 128) * KTOT + kt * 64;
        char* d = smem + c * 65536 + s * 16384 + wbase;
        gload16(d,        src);
        gload16(d + 8192, src + (long long)64 * KTOT);
    };
    auto stB = [&](int c, int s, int kt) {
        const unsigned short* src = gB + (long long)(s * 128) * KTOT + kt * 64;
        char* d = smem + c * 65536 + 32768 + s * 16384 + wbase;
        gload16(d,        src);
        gload16(d + 8192, src + (long long)64 * KTOT);
    };

    stA(0, 0, 0); stA(0, 1, 0); stB(0, 0, 0); stB(0, 1, 0);
    stA(1, 0, 1); stA(1, 1, 1);
    asm volatile("s_waitcnt vmcnt(4)" ::: "memory");
    __builtin_amdgcn_s_barrier();
    __builtin_amdgcn_sched_barrier(0);

#pragma unroll
    for (int kt = 0; kt < NT_; ++kt) {
        const int c = kt & 1;
        const char* bufc = smem + c * 65536;
        bf16x8 a0[4], a1[4], b0[4], b1[4];

        // last tile: overlap SC-epilogue staging into the idle buffer (c^1)
        if (SC && kt == NT_ - 1 && g < E) {
            float* qpl  = (float*)(smem + QBUF);
            int*   tidl = (int*)(smem + QBUF + NT * 256 * 4);
            for (int i = tid; i < NT * 256; i += 512) {
                int tt = i >> 8, cc = i & 255;
                qpl[i] = qp[((long long)(g * NT + tt)) * H2 + gn + cc];
            }
            if (tid < 256) tidl[tid] = task_id[gm + tid];
        }

        // ---- ph0: read A-half0 + all B; issue next-tile B staging ----
#pragma unroll
        for (int m = 0; m < 4; ++m) {
            const char* base = bufc + aRow + m * (16 * 128);
            a0[m] = *(const bf16x8*)(base + cs0);
            a1[m] = *(const bf16x8*)(base + cs1);
        }
#pragma unroll
        for (int n = 0; n < 4; ++n) {
            const char* base = bufc + bRow + n * (16 * 128);
            b0[n] = *(const bf16x8*)(base + cs0);
            b1[n] = *(const bf16x8*)(base + cs1);
        }
        if (kt + 1 < NT_) { stB(c ^ 1, 0, kt + 1); stB(c ^ 1, 1, kt + 1); }
        __builtin_amdgcn_s_setprio(1);
#pragma unroll
        for (int m = 0; m < 4; ++m)
#pragma unroll
            for (int n = 0; n < 4; ++n) {
                acc[m][n] = __builtin_amdgcn_mfma_f32_16x16x32_bf16(a0[m], b0[n], acc[m][n], 0, 0, 0);
                acc[m][n] = __builtin_amdgcn_mfma_f32_16x16x32_bf16(a1[m], b1[n], acc[m][n], 0, 0, 0);
            }
        __builtin_amdgcn_s_setprio(0);

        // ---- ph1: read A-half1; free buffer; stage tile t+2 A-units ----
#pragma unroll
        for (int m = 0; m < 4; ++m) {
            const char* base = bufc + aRow + (64 + m * 16) * 128;
            a0[m] = *(const bf16x8*)(base + cs0);
            a1[m] = *(const bf16x8*)(base + cs1);
        }
        asm volatile("s_waitcnt lgkmcnt(0)" ::: "memory");
        __builtin_amdgcn_sched_barrier(0);
        if (kt + 2 < NT_) {
            __builtin_amdgcn_s_barrier();
            __builtin_amdgcn_sched_barrier(0);
            stA(c, 0, kt + 2); stA(c, 1, kt + 2);
        }
        __builtin_amdgcn_s_setprio(1);
#pragma unroll
        for (int m = 0; m < 4; ++m)
#pragma unroll
            for (int n = 0; n < 4; ++n) {
                acc[4 + m][n] = __builtin_amdgcn_mfma_f32_16x16x32_bf16(a0[m], b0[n], acc[4 + m][n], 0, 0, 0);
                acc[4 + m][n] = __builtin_amdgcn_mfma_f32_16x16x32_bf16(a1[m], b1[n], acc[4 + m][n], 0, 0, 0);
            }
        __builtin_amdgcn_s_setprio(0);

        if (kt + 1 < NT_) {
            if (kt + 2 < NT_) { asm volatile("s_waitcnt vmcnt(4)" ::: "memory"); }
            else              { asm volatile("s_waitcnt vmcnt(0)" ::: "memory"); }
            __builtin_amdgcn_sched_barrier(0);
            __builtin_amdgcn_s_barrier();
            __builtin_amdgcn_sched_barrier(0);
        }
    }

    const int orow0 = gm + wr * 128 + lk * 4;
    const int ocol0 = gn + wc * 64 + lr;
    float bv[4];
#pragma unroll
    for (int ni = 0; ni < 4; ++ni) bv[ni] = bias[gn + wc * 64 + lr + ni * 16];

    if (SC && g < E) {
        __syncthreads();                       // staging writes visible to all waves
        const float* qpl  = (const float*)(smem + QBUF);
        const int*   tidl = (const int*)(smem + QBUF + NT * 256 * 4);

        const int rbase = wr * 128 + lk * 4;
        const int cbase = wc * 64 + lr;
#pragma unroll
        for (int mi = 0; mi < 8; ++mi) {
#pragma unroll
            for (int r = 0; r < 4; ++r) {
                int trow = tidl[rbase + mi * 16 + r];
                float rp = 0.f;
#pragma unroll
                for (int ni = 0; ni < 4; ++ni) {
                    float v = acc[mi][ni][r] + bv[ni];
                    v = fmaxf(v, 0.f);
                    rp += v * qpl[trow * 256 + cbase + ni * 16];
                }
                rp += __shfl_xor(rp, 1);
                rp += __shfl_xor(rp, 2);
                rp += __shfl_xor(rp, 4);
                rp += __shfl_xor(rp, 8);
                if (lr == 0)
                    spart[(((long long)g * Bn + orow0 + mi * 16 + r) << 3)
                          + (wc << 1) + blockIdx.x] = rp;
            }
        }
    } else {
#pragma unroll
        for (int mi = 0; mi < 8; ++mi)
#pragma unroll
            for (int ni = 0; ni < 4; ++ni)
#pragma unroll
                for (int r = 0; r < 4; ++r) {
                    float v = acc[mi][ni][r] + bv[ni];
                    if (ACTF == 1) v = fmaxf(v, 0.f);
                    long long off = (long long)(orow0 + mi * 16 + r) * ldc + ocol0 + ni * 16;
                    if (OUTF == 0) Cf[off] = v;
                    else           Cb[off] = f2bf(v);
                }
    }
}

// ---------------- attn: scores from spart partials, softmax, weighted vals sum, loss ----------------
__global__ __launch_bounds__(256) void attn_kernel(
    const float* __restrict__ spart, const float* __restrict__ qb,
    const int* __restrict__ task_id, const unsigned short* __restrict__ vals,
    unsigned short* __restrict__ tower_in, float* __restrict__ loss_partial)
{
    int wv   = threadIdx.x >> 6;
    int lane = threadIdx.x & 63;
    int b    = blockIdx.x * 4 + wv;
    int t    = task_id[b];

    float s[E];
#pragma unroll
    for (int e = 0; e < E; ++e) {
        const float4* sp = (const float4*)(spart + (((long long)e * Bn + b) << 3));
        float4 p0 = sp[0], p1 = sp[1];
        s[e] = p0.x + p0.y + p0.z + p0.w + p1.x + p1.y + p1.z + p1.w + qb[e * NT + t];
    }

    float m = s[0];
#pragma unroll
    for (int e = 1; e < E; ++e) m = fmaxf(m, s[e]);
    float wgt[E];
    float sum = 0.f;
#pragma unroll
    for (int e = 0; e < E; ++e) { wgt[e] = expf(s[e] - m); sum += wgt[e]; }
    float inv = 1.f / sum;

    int d0 = lane * 4;
    float4 acc = make_float4(0.f, 0.f, 0.f, 0.f);
    float lb = 0.f;
#pragma unroll
    for (int e = 0; e < E; ++e) {
        float we = wgt[e] * inv;
        uint2 vv = *(const uint2*)&vals[((long long)e * Bn + b) * D + d0];
        acc.x += we * __uint_as_float(vv.x << 16);
        acc.y += we * __uint_as_float(vv.x & 0xffff0000u);
        acc.z += we * __uint_as_float(vv.y << 16);
        acc.w += we * __uint_as_float(vv.y & 0xffff0000u);
        lb += fminf(fmaxf(logf(we + 1e-10f), -6.f), 0.f);
    }
    ushort4 o;
    o.x = f2bf(acc.x); o.y = f2bf(acc.y); o.z = f2bf(acc.z); o.w = f2bf(acc.w);
    *(ushort4*)&tower_in[(long long)b * D + d0] = o;

    __shared__ float sm[4];
    if (lane == 0) sm[wv] = lb;
    __syncthreads();
    if (threadIdx.x == 0)
        loss_partial[blockIdx.x] = sm[0] + sm[1] + sm[2] + sm[3];
}

// ---------------- qfin: out[b] = sum(qpart[b][0..7])+tb3 ; last block: loss ----------------
__global__ __launch_bounds__(256) void qfin_kernel(
    const float* __restrict__ qpart, const float* __restrict__ tb3,
    float* __restrict__ out, const float* __restrict__ lossp)
{
    if (blockIdx.x == Bn / 256) {
        float s = 0.f;
        for (int i = threadIdx.x; i < Bn / 4; i += 256) s += lossp[i];
#pragma unroll
        for (int off = 32; off > 0; off >>= 1) s += __shfl_xor(s, off, 64);
        __shared__ float sm[4];
        if ((threadIdx.x & 63) == 0) sm[threadIdx.x >> 6] = s;
        __syncthreads();
        if (threadIdx.x == 0) out[Bn] = (-0.3f / Bn) * (sm[0] + sm[1] + sm[2] + sm[3]);
        return;
    }
    int b = blockIdx.x * 256 + threadIdx.x;
    const float4* qq = (const float4*)&qpart[b * 8];
    float4 a0 = qq[0], a1 = qq[1];
    out[b] = a0.x + a0.y + a0.z + a0.w + a1.x + a1.y + a1.z + a1.w + tb3[0];
}

extern "C" void kernel_launch(void* const* d_in, const int* in_sizes, int n_in,
                              void* d_out, int out_size, void* d_ws, size_t ws_size,
                              hipStream_t stream) {
    const float* state_feat = (const float*)d_in[0];
    const float* act        = (const float*)d_in[1];
    const int*   task_id    = (const int*)d_in[2];
    const float* rep_W1 = (const float*)d_in[3];
    const float* rep_b1 = (const float*)d_in[4];
    const float* rep_W2 = (const float*)d_in[5];
    const float* rep_b2 = (const float*)d_in[6];
    const float* emb    = (const float*)d_in[7];
    const float* kW1 = (const float*)d_in[8];
    const float* kb1 = (const float*)d_in[9];
    const float* kW2 = (const float*)d_in[10];
    const float* kb2 = (const float*)d_in[11];
    const float* vW1 = (const float*)d_in[12];
    const float* vb1 = (const float*)d_in[13];
    const float* vW2 = (const float*)d_in[14];
    const float* vb2 = (const float*)d_in[15];
    const float* tW1 = (const float*)d_in[16];
    const float* tb1 = (const float*)d_in[17];
    const float* tW2 = (const float*)d_in[18];
    const float* tb2 = (const float*)d_in[19];
    const float* tW3 = (const float*)d_in[20];
    const float* tb3 = (const float*)d_in[21];
    float* out = (float*)d_out;

    // ---- workspace (~92 MB) ----
    char* p = (char*)d_ws;
    auto alloc = [&](size_t bytes) {
        char* r = p;
        p += (bytes + 255) & ~(size_t)255;
        return r;
    };
    unsigned short* x      = (unsigned short*)alloc((size_t)Bn * KPAD * 2);
    unsigned short* repW1T = (unsigned short*)alloc((size_t)H1 * KPAD * 2);
    unsigned short* repW2T = (unsigned short*)alloc((size_t)H1 * H1 * 2);
    unsigned short* w1T    = (unsigned short*)alloc((size_t)2 * E * H2 * H1 * 2);  // K then V
    unsigned short* w2T    = (unsigned short*)alloc((size_t)E * D * H2 * 2);       // V only
    unsigned short* tW1T   = (unsigned short*)alloc((size_t)D * D * 2);
    unsigned short* tW2T   = (unsigned short*)alloc((size_t)D * D * 2);
    float*          b1cat  = (float*)alloc((size_t)2 * E * H2 * 4);
    float*          qp     = (float*)alloc((size_t)E * NT * H2 * 4);
    float*          qb     = (float*)alloc((size_t)E * NT * 4);
    char*           h1zone = alloc((size_t)Bn * H1 * 2);
    unsigned short* rep    = (unsigned short*)alloc((size_t)Bn * H1 * 2);
    unsigned short* hkv    = (unsigned short*)alloc((size_t)2 * E * Bn * H2 * 2);
    unsigned short* vals   = (unsigned short*)alloc((size_t)E * Bn * D * 2);
    float*          spart  = (float*)alloc((size_t)E * Bn * 8 * 4);
    float*          qpart  = (float*)alloc((size_t)Bn * 8 * 4);
    float*          lossp  = (float*)alloc((size_t)(Bn / 4) * 4);

    unsigned short* h1       = (unsigned short*)h1zone;
    unsigned short* tower_in = (unsigned short*)h1zone;
    unsigned short* t1       = (unsigned short*)(h1zone + (size_t)Bn * D * 2);
    unsigned short* hv = hkv + (size_t)E * Bn * H2;

    // ---- 1. prep_all: transposes + x-cast + qproj + bias concat (1 launch) ----
    TD2Arr da;
    int startAcc = 0;
    auto setd = [&](int i, const float* W, unsigned short* WT, int K, int Kpad, int N,
                    long long gsW, long long gsO, int groups) {
        TD2& dd = da.d[i];
        dd.W = W; dd.WT = WT; dd.K = K; dd.Kpad = Kpad; dd.N = N;
        dd.gsW = gsW; dd.gsO = gsO;
        dd.tilesN = N / 64;
        dd.perG = ((Kpad + 63) / 64) * dd.tilesN;
        dd.start = startAcc;
        startAcc += dd.perG * groups;
    };
    setd(0, rep_W1, repW1T, IN, KPAD, H1, 0, 0, 1);
    setd(1, rep_W2, repW2T, H1, H1, H1, 0, 0, 1);
    setd(2, kW1, w1T,                       H1, H1, H2, (long long)H1 * H2, (long long)H2 * H1, E);
    setd(3, vW1, w1T + (size_t)E * H2 * H1, H1, H1, H2, (long long)H1 * H2, (long long)H2 * H1, E);
    setd(4, vW2, w2T,                       H2, H2, D, (long long)H2 * D, (long long)D * H2, E);
    setd(5, tW1, tW1T, D, D, D, 0, 0, 1);
    setd(6, tW2, tW2T, D, D, D, 0, 0, 1);
    da.d[7] = da.d[6];
    da.d[7].start = 0x7fffffff;
    int totalBlocks = startAcc + PREPB + 17 + 32;
    prep_all<<<totalBlocks, 256, 0, stream>>>(
        da, startAcc, state_feat, act, x, kW2, kb2, emb, qp, qb, kb1, vb1, b1cat);

    // ---- 2. rep MLP (64x128-tile pipelined) ----
    gemm64x128<KPAD, 1, 1><<<dim3(H1 / 128, Bn / 64, 1), 256, 0, stream>>>(
        x, repW1T, rep_b1, h1, H1, 0, 0, 0, 0);
    gemm64x128<H1, 0, 1><<<dim3(H1 / 128, Bn / 64, 1), 256, 0, stream>>>(
        h1, repW2T, rep_b2, rep, H1, 0, 0, 0, 0);

    // ---- 3. expert L1 K+V fused (256^2 R12 schedule, scores in epilogue); L2 V-only ----
    gemm256<H1, 1, 1, 1><<<dim3(H2 / 256, Bn / 256, 2 * E), 512, 0, stream>>>(
        rep, w1T, b1cat, hkv, H2,
        0, (long long)H2 * H1, H2, (long long)Bn * H2,
        task_id, qp, spart);
    gemm64x128<H2, 0, 1><<<dim3(D / 128, Bn / 64, E), 256, 0, stream>>>(
        hv, w2T, vb2, vals, D,
        (long long)Bn * H2, (long long)D * H2, D, (long long)Bn * D);

    // ---- 4. attention (scores from spart partials) ----
    attn_kernel<<<Bn / 4, 256, 0, stream>>>(
        spart, qb, task_id, vals, tower_in, lossp);

    // ---- 5. tower (64x128-tile; tower2 fuses the tW3 dot) ----
    gemm64x128<D, 1, 1><<<dim3(D / 128, Bn / 64, 1), 256, 0, stream>>>(
        tower_in, tW1T, tb1, t1, D, 0, 0, 0, 0);
    gemm64x128<D, 1, 2><<<dim3(D / 128, Bn / 64, 1), 256, 0, stream>>>(
        t1, tW2T, tb2, nullptr, D, 0, 0, 0, 0, tW3, qpart);

    // ---- 6. q + loss ----
    qfin_kernel<<<Bn / 256 + 1, 256, 0, stream>>>(qpart, tb3, out, lossp);
}

// Round 16
// 155.344 us; speedup vs baseline: 1.0522x; 1.0040x over previous
//
#include <hip/hip_runtime.h>

constexpr int Bn   = 4096;
constexpr int OBS  = 390;
constexpr int ACTN = 20;
constexpr int IN   = 410;   // OBS + ACTN
constexpr int KPAD = 448;   // IN padded to multiple of 64
constexpr int E    = 8;
constexpr int NT   = 10;
constexpr int H1   = 1024;
constexpr int H2   = 512;
constexpr int D    = 256;

typedef __bf16 bf16x8 __attribute__((ext_vector_type(8)));
typedef float  f32x4  __attribute__((ext_vector_type(4)));
typedef unsigned short u16x8 __attribute__((ext_vector_type(8)));

__device__ __forceinline__ unsigned short f2bf(float f) {
    unsigned int u = __float_as_uint(f);
    unsigned int r = u + 0x7fffu + ((u >> 16) & 1u);   // RNE
    return (unsigned short)(r >> 16);
}
__device__ __forceinline__ void gload16(void* lds_dst, const void* g_src) {
    __builtin_amdgcn_global_load_lds(
        (const __attribute__((address_space(1))) void*)g_src,
        (__attribute__((address_space(3))) void*)lds_dst,
        16, 0, 0);
}
// T1: bijective XCD-aware block remap (identity if nwg % 8 != 0)
__device__ __forceinline__ void xcd_swz(int& bx, int& by, int& bz) {
    int nx = gridDim.x, ny = gridDim.y, nz = gridDim.z;
    int nwg = nx * ny * nz;
    int flat = blockIdx.x + nx * (blockIdx.y + ny * blockIdx.z);
    if ((nwg & 7) == 0) {
        int chunk = nwg >> 3;
        flat = (flat & 7) * chunk + (flat >> 3);
    }
    bx = flat % nx;
    int rest = flat / nx;
    by = rest % ny;
    bz = rest / ny;
}

// ---------------- prep_all: tc64 transposes + x-cast + qproj + bias concat, ONE launch ----------------
struct TD2 {
    const float* W;
    unsigned short* WT;
    int K, Kpad, N;
    long long gsW, gsO;
    int tilesN, perG, start;
};
struct TD2Arr { TD2 d[8]; };

constexpr int XCH    = KPAD / 8;            // 56 bf16x8 chunks per row
constexpr int PREPB  = (Bn * XCH) / 256;    // 896 blocks for x-cast

__global__ __launch_bounds__(256) void prep_all(
    TD2Arr da, int tcb,
    const float* __restrict__ sf, const float* __restrict__ ac,
    unsigned short* __restrict__ x,
    const float* __restrict__ kW2, const float* __restrict__ kb2,
    const float* __restrict__ emb, float* __restrict__ qp, float* __restrict__ qb,
    const float* __restrict__ kb1, const float* __restrict__ vb1,
    float* __restrict__ b1cat)
{
    __shared__ float tile[64][68];
    int bid = blockIdx.x;
    int t = threadIdx.x;

    if (bid < tcb) {
        int i = 0;
#pragma unroll
        for (int j = 1; j < 8; ++j) if (bid >= da.d[j].start) i = j;
        TD2 dd = da.d[i];
        int local = bid - dd.start;
        int g   = local / dd.perG;
        int rem = local - g * dd.perG;
        int kt  = rem / dd.tilesN;
        int nt  = rem - kt * dd.tilesN;
        const float* W = dd.W + (long long)g * dd.gsW;
        unsigned short* WT = dd.WT + (long long)g * dd.gsO;
        int k0 = kt * 64, n0 = nt * 64;
        {
            int kl  = t >> 4;
            int nl4 = (t & 15) * 4;
#pragma unroll
            for (int r = 0; r < 4; ++r) {
                int k = k0 + kl + r * 16;
                float4 v = make_float4(0.f, 0.f, 0.f, 0.f);
                if (k < dd.K) v = *(const float4*)(W + (long long)k * dd.N + n0 + nl4);
                *(float4*)&tile[kl + r * 16][nl4] = v;
            }
        }
        __syncthreads();
        int nl = t >> 2, kc = (t & 3) * 16;
        if (k0 + kc < dd.Kpad) {
            u16x8 o0, o1;
#pragma unroll
            for (int j = 0; j < 8; ++j) {
                o0[j] = f2bf(tile[kc + j][nl]);
                o1[j] = f2bf(tile[kc + 8 + j][nl]);
            }
            unsigned short* dst = WT + (long long)(n0 + nl) * dd.Kpad + k0 + kc;
            *(u16x8*)dst       = o0;
            *(u16x8*)(dst + 8) = o1;
        }
        return;
    }
    int bid2 = bid - tcb;
    if (bid2 < PREPB) {
        int cidx = bid2 * 256 + t;           // chunk index, 8 bf16 per chunk
        int b  = cidx / XCH;
        int cc = cidx - b * XCH;
        int k0 = cc * 8;
        u16x8 o;
        if (cc < 48) {                       // k0+7 <= 383 < OBS: pure state_feat
            const float* s = sf + (long long)b * OBS + k0;   // 8B-aligned
#pragma unroll
            for (int j = 0; j < 4; ++j) {
                float2 v = *(const float2*)(s + j * 2);
                o[j * 2]     = f2bf(v.x);
                o[j * 2 + 1] = f2bf(v.y);
            }
        } else {
#pragma unroll
            for (int j = 0; j < 8; ++j) {
                int k = k0 + j;
                float v = 0.f;
                if (k < OBS) v = sf[(long long)b * OBS + k];
                else if (k < IN) v = ac[b * ACTN + (k - OBS)];
                o[j] = f2bf(v);
            }
        }
        *(u16x8*)(x + (long long)b * KPAD + k0) = o;
        return;
    }
    if (bid2 < PREPB + 17) {
        int qbid = bid2 - PREPB;
        float* tq = &tile[0][0];   // [NT*D] = 2560 floats fits
        for (int i = t; i < NT * D; i += 256) tq[i] = tanhf(emb[i]);
        __syncthreads();
        if (qbid < 16) {
            int e = qbid >> 1;
            int h = (qbid & 1) * 256 + t;
            const float4* row = (const float4*)(kW2 + ((long long)e * H2 + h) * D);
            float acc[NT] = {};
            for (int d4 = 0; d4 < D / 4; ++d4) {
                float4 wv = row[d4];
#pragma unroll
                for (int tt = 0; tt < NT; ++tt)
                    acc[tt] += wv.x * tq[tt * D + d4 * 4] + wv.y * tq[tt * D + d4 * 4 + 1]
                             + wv.z * tq[tt * D + d4 * 4 + 2] + wv.w * tq[tt * D + d4 * 4 + 3];
            }
#pragma unroll
            for (int tt = 0; tt < NT; ++tt)
                qp[((long long)e * NT + tt) * H2 + h] = acc[tt];
        } else if (t < E * NT) {
            int e = t / NT, tt = t - e * NT;
            float s = 0.f;
            for (int d = 0; d < D; ++d) s += kb2[e * D + d] * tq[tt * D + d];
            qb[e * NT + tt] = s;
        }
        return;
    }
    int i = (bid2 - PREPB - 17) * 256 + t;   // < 2*E*H2 = 8192
    b1cat[i] = (i < E * H2) ? kb1[i] : vb1[i - E * H2];
}

// ---------------- 64x128 pipelined bf16 GEMM (R12 2-phase, BK=64) + T1 swizzle ----------------
// 4 waves side-by-side in N (each 64M x 32N, acc[4][2]). Grid (N/128, M/64, groups).
// OUTF: 0=f32 C, 1=bf16 C, 2=no C store, per-row tW3 dot -> qpart[row][bx*4+w]
template <int KT, int ACTF, int OUTF>
__global__ __launch_bounds__(256, 3) void gemm64x128(
    const unsigned short* __restrict__ A, const unsigned short* __restrict__ BT,
    const float* __restrict__ bias, void* __restrict__ Cout,
    int ldc, long long gsA, long long gsBT, long long gsBias, long long gsC,
    const float* __restrict__ tW3 = nullptr, float* __restrict__ qpart = nullptr)
{
    constexpr int NTK = KT / 64;
    static_assert(NTK >= 2, "KT must be >= 128");

    int bx, by, bz;
    xcd_swz(bx, by, bz);
    const int g = bz;
    A    += (long long)g * gsA;
    BT   += (long long)g * gsBT;
    bias += (long long)g * gsBias;
    float*          Cf = (float*)Cout + (long long)g * gsC;
    unsigned short* Cb = (unsigned short*)Cout + (long long)g * gsC;

    __shared__ __align__(16) char smem[49152];
    const int tid = threadIdx.x;
    const int l  = tid & 63, lr = l & 15, lk = l >> 4;
    const int w  = tid >> 6;
    const int gm = by * 64, gn = bx * 128;

    const int srow = tid >> 3;                    // 0..31
    const int cg   = (tid & 7) ^ (srow & 7);      // pre-swizzled global chunk
    const unsigned short* gA = A  + (long long)(gm + srow) * KT + cg * 8;
    const unsigned short* gB = BT + (long long)(gn + srow) * KT + cg * 8;
    const int wb = w * 1024;

    const int cs0 = ((0 | lk) ^ (lr & 7)) * 16;
    const int cs1 = ((4 | lk) ^ (lr & 7)) * 16;
    const int aRow = lr * 128;
    const int bRow = 8192 + (w * 32 + lr) * 128;

    f32x4 acc[4][2] = {};

    auto stA = [&](int c, int kt) {
#pragma unroll
        for (int j = 0; j < 2; ++j)
            gload16(smem + c * 24576 + j * 4096 + wb,
                    gA + (long long)(j * 32) * KT + kt * 64);
    };
    auto stB = [&](int c, int kt) {
#pragma unroll
        for (int j = 0; j < 4; ++j)
            gload16(smem + c * 24576 + 8192 + j * 4096 + wb,
                    gB + (long long)(j * 32) * KT + kt * 64);
    };

    // prologue: A(0)=2, B(0)=4, A(1)=2; vmcnt(2) retires tile0's 6, keeps A(1)
    stA(0, 0); stB(0, 0); stA(1, 1);
    asm volatile("s_waitcnt vmcnt(2)" ::: "memory");
    __builtin_amdgcn_s_barrier();
    __builtin_amdgcn_sched_barrier(0);

#pragma unroll
    for (int kt = 0; kt < NTK; ++kt) {
        const int c = kt & 1;
        const char* bufc = smem + c * 24576;
        bf16x8 a[4][2], b[1][2], b2[1][2];

        // ph0: read A-all + b(nf0); stage B(kt+1) -> buf c^1; 8 MFMA
#pragma unroll
        for (int m = 0; m < 4; ++m) {
            const char* base = bufc + aRow + m * 2048;
            a[m][0] = *(const bf16x8*)(base + cs0);
            a[m][1] = *(const bf16x8*)(base + cs1);
        }
        {
            const char* base = bufc + bRow;
            b[0][0] = *(const bf16x8*)(base + cs0);
            b[0][1] = *(const bf16x8*)(base + cs1);
        }
        if (kt + 1 < NTK) stB(c ^ 1, kt + 1);
        __builtin_amdgcn_s_setprio(1);
#pragma unroll
        for (int ks = 0; ks < 2; ++ks)
#pragma unroll
            for (int m = 0; m < 4; ++m)
                acc[m][0] = __builtin_amdgcn_mfma_f32_16x16x32_bf16(
                    a[m][ks], b[0][ks], acc[m][0], 0, 0, 0);
        __builtin_amdgcn_s_setprio(0);

        // ph1: read b(nf1); free buf c; stage A(kt+2) -> buf c; 8 MFMA
        {
            const char* base = bufc + bRow + 2048;
            b2[0][0] = *(const bf16x8*)(base + cs0);
            b2[0][1] = *(const bf16x8*)(base + cs1);
        }
        asm volatile("s_waitcnt lgkmcnt(0)" ::: "memory");
        __builtin_amdgcn_sched_barrier(0);
        if (kt + 2 < NTK) {
            __builtin_amdgcn_s_barrier();
            __builtin_amdgcn_sched_barrier(0);
            stA(c, kt + 2);
        }
        __builtin_amdgcn_s_setprio(1);
#pragma unroll
        for (int ks = 0; ks < 2; ++ks)
#pragma unroll
            for (int m = 0; m < 4; ++m)
                acc[m][1] = __builtin_amdgcn_mfma_f32_16x16x32_bf16(
                    a[m][ks], b2[0][ks], acc[m][1], 0, 0, 0);
        __builtin_amdgcn_s_setprio(0);

        // boundary: tile kt+1 (A=2,B=4) landed; A(kt+2)=2 in flight
        if (kt + 1 < NTK) {
            if (kt + 2 < NTK) { asm volatile("s_waitcnt vmcnt(2)" ::: "memory"); }
            else              { asm volatile("s_waitcnt vmcnt(0)" ::: "memory"); }
            __builtin_amdgcn_sched_barrier(0);
            __builtin_amdgcn_s_barrier();
            __builtin_amdgcn_sched_barrier(0);
        }
    }

    const int orow0 = gm + lk * 4;
    const int ocol0 = gn + w * 32 + lr;
    float bv[2];
#pragma unroll
    for (int nf = 0; nf < 2; ++nf) bv[nf] = bias[gn + w * 32 + lr + nf * 16];

    if (OUTF == 2) {
        float tw3v[2];
#pragma unroll
        for (int nf = 0; nf < 2; ++nf) tw3v[nf] = tW3[gn + w * 32 + lr + nf * 16];
#pragma unroll
        for (int mi = 0; mi < 4; ++mi)
#pragma unroll
            for (int r = 0; r < 4; ++r) {
                float part = 0.f;
#pragma unroll
                for (int nf = 0; nf < 2; ++nf) {
                    float v = acc[mi][nf][r] + bv[nf];
                    if (ACTF == 1) v = fmaxf(v, 0.f);
                    part += v * tw3v[nf];
                }
                part += __shfl_xor(part, 1);
                part += __shfl_xor(part, 2);
                part += __shfl_xor(part, 4);
                part += __shfl_xor(part, 8);
                if (lr == 0)
                    qpart[(orow0 + mi * 16 + r) * 8 + bx * 4 + w] = part;
            }
    } else {
#pragma unroll
        for (int mi = 0; mi < 4; ++mi)
#pragma unroll
            for (int nf = 0; nf < 2; ++nf)
#pragma unroll
                for (int r = 0; r < 4; ++r) {
                    float v = acc[mi][nf][r] + bv[nf];
                    if (ACTF == 1) v = fmaxf(v, 0.f);
                    long long off = (long long)(orow0 + mi * 16 + r) * ldc + ocol0 + nf * 16;
                    if (OUTF == 0) Cf[off] = v;
                    else           Cb[off] = f2bf(v);
                }
    }
}

// ---------------- 256x256 8-wave pipelined bf16 GEMM (R12-proven 2-phase) + T1 swizzle ----------------
// SC=1: groups g<E score-only; qp slice + task_id staged into the idle LDS buffer
// DURING the last K-tile (buffer c^1 proven drained by the preceding boundary).
template <int KTOT, int ACTF, int OUTF, int SC>
__global__ __launch_bounds__(512, 2) void gemm256(
    const unsigned short* __restrict__ A, const unsigned short* __restrict__ BT,
    const float* __restrict__ bias, void* __restrict__ Cout,
    int ldc, long long gsA, long long gsBT, long long gsBias, long long gsC,
    const int* __restrict__ task_id, const float* __restrict__ qp,
    float* __restrict__ spart)
{
    constexpr int NT_ = KTOT / 64;
    static_assert(NT_ >= 4 && (NT_ % 2) == 0, "KTOT must be multiple of 128");
    constexpr int QBUF = (((NT_ - 1) & 1) ^ 1) * 65536;   // idle buffer during last tile

    int bx, by, bz;
    xcd_swz(bx, by, bz);
    const int g = bz;
    A    += (long long)g * gsA;
    BT   += (long long)g * gsBT;
    bias += (long long)g * gsBias;
    float*          Cf = (float*)Cout + (long long)g * gsC;
    unsigned short* Cb = (unsigned short*)Cout + (long long)g * gsC;

    __shared__ __align__(16) char smem[131072];

    const int tid = threadIdx.x;
    const int l  = tid & 63;
    const int lr = l & 15, lk = l >> 4;
    const int w  = tid >> 6;
    const int wr = w >> 2, wc = w & 3;
    const int gm = by * 256, gn = bx * 256;

    const int srow = tid >> 3;
    const int cg   = (tid & 7) ^ (srow & 7);
    const unsigned short* gA = A  + (long long)(gm + srow) * KTOT + cg * 8;
    const unsigned short* gB = BT + (long long)(gn + srow) * KTOT + cg * 8;
    const int wbase = (tid & ~63) * 16;

    const int cs0 = ((0 | lk) ^ (lr & 7)) * 16;
    const int cs1 = ((4 | lk) ^ (lr & 7)) * 16;
    const int aRow = wr * 16384 + lr * 128;
    const int bRow = 32768 + (wc >> 1) * 16384 + ((wc & 1) * 64 + lr) * 128;

    f32x4 acc[8][4] = {};

    auto stA = [&](int c, int s, int kt) {
        const unsigned short* src = gA + (long long)(s * 128) * KTOT + kt * 64;
        char* d = smem + c * 65536 + s * 16384 + wbase;
        gload16(d,        src);
        gload16(d + 8192, src + (long long)64 * KTOT);
    };
    auto stB = [&](int c, int s, int kt) {
        const unsigned short* src = gB + (long long)(s * 128) * KTOT + kt * 64;
        char* d = smem + c * 65536 + 32768 + s * 16384 + wbase;
        gload16(d,        src);
        gload16(d + 8192, src + (long long)64 * KTOT);
    };

    stA(0, 0, 0); stA(0, 1, 0); stB(0, 0, 0); stB(0, 1, 0);
    stA(1, 0, 1); stA(1, 1, 1);
    asm volatile("s_waitcnt vmcnt(4)" ::: "memory");
    __builtin_amdgcn_s_barrier();
    __builtin_amdgcn_sched_barrier(0);

#pragma unroll
    for (int kt = 0; kt < NT_; ++kt) {
        const int c = kt & 1;
        const char* bufc = smem + c * 65536;
        bf16x8 a0[4], a1[4], b0[4], b1[4];

        // last tile: overlap SC-epilogue staging into the idle buffer (c^1)
        if (SC && kt == NT_ - 1 && g < E) {
            float* qpl  = (float*)(smem + QBUF);
            int*   tidl = (int*)(smem + QBUF + NT * 256 * 4);
            for (int i = tid; i < NT * 256; i += 512) {
                int tt = i >> 8, cc = i & 255;
                qpl[i] = qp[((long long)(g * NT + tt)) * H2 + gn + cc];
            }
            if (tid < 256) tidl[tid] = task_id[gm + tid];
        }

        // ---- ph0: read A-half0 + all B; issue next-tile B staging ----
#pragma unroll
        for (int m = 0; m < 4; ++m) {
            const char* base = bufc + aRow + m * (16 * 128);
            a0[m] = *(const bf16x8*)(base + cs0);
            a1[m] = *(const bf16x8*)(base + cs1);
        }
#pragma unroll
        for (int n = 0; n < 4; ++n) {
            const char* base = bufc + bRow + n * (16 * 128);
            b0[n] = *(const bf16x8*)(base + cs0);
            b1[n] = *(const bf16x8*)(base + cs1);
        }
        if (kt + 1 < NT_) { stB(c ^ 1, 0, kt + 1); stB(c ^ 1, 1, kt + 1); }
        __builtin_amdgcn_s_setprio(1);
#pragma unroll
        for (int m = 0; m < 4; ++m)
#pragma unroll
            for (int n = 0; n < 4; ++n) {
                acc[m][n] = __builtin_amdgcn_mfma_f32_16x16x32_bf16(a0[m], b0[n], acc[m][n], 0, 0, 0);
                acc[m][n] = __builtin_amdgcn_mfma_f32_16x16x32_bf16(a1[m], b1[n], acc[m][n], 0, 0, 0);
            }
        __builtin_amdgcn_s_setprio(0);

        // ---- ph1: read A-half1; free buffer; stage tile t+2 A-units ----
#pragma unroll
        for (int m = 0; m < 4; ++m) {
            const char* base = bufc + aRow + (64 + m * 16) * 128;
            a0[m] = *(const bf16x8*)(base + cs0);
            a1[m] = *(const bf16x8*)(base + cs1);
        }
        asm volatile("s_waitcnt lgkmcnt(0)" ::: "memory");
        __builtin_amdgcn_sched_barrier(0);
        if (kt + 2 < NT_) {
            __builtin_amdgcn_s_barrier();
            __builtin_amdgcn_sched_barrier(0);
            stA(c, 0, kt + 2); stA(c, 1, kt + 2);
        }
        __builtin_amdgcn_s_setprio(1);
#pragma unroll
        for (int m = 0; m < 4; ++m)
#pragma unroll
            for (int n = 0; n < 4; ++n) {
                acc[4 + m][n] = __builtin_amdgcn_mfma_f32_16x16x32_bf16(a0[m], b0[n], acc[4 + m][n], 0, 0, 0);
                acc[4 + m][n] = __builtin_amdgcn_mfma_f32_16x16x32_bf16(a1[m], b1[n], acc[4 + m][n], 0, 0, 0);
            }
        __builtin_amdgcn_s_setprio(0);

        if (kt + 1 < NT_) {
            if (kt + 2 < NT_) { asm volatile("s_waitcnt vmcnt(4)" ::: "memory"); }
            else              { asm volatile("s_waitcnt vmcnt(0)" ::: "memory"); }
            __builtin_amdgcn_sched_barrier(0);
            __builtin_amdgcn_s_barrier();
            __builtin_amdgcn_sched_barrier(0);
        }
    }

    const int orow0 = gm + wr * 128 + lk * 4;
    const int ocol0 = gn + wc * 64 + lr;
    float bv[4];
#pragma unroll
    for (int ni = 0; ni < 4; ++ni) bv[ni] = bias[gn + wc * 64 + lr + ni * 16];

    if (SC && g < E) {
        __syncthreads();                       // staging writes visible to all waves
        const float* qpl  = (const float*)(smem + QBUF);
        const int*   tidl = (const int*)(smem + QBUF + NT * 256 * 4);

        const int rbase = wr * 128 + lk * 4;
        const int cbase = wc * 64 + lr;
#pragma unroll
        for (int mi = 0; mi < 8; ++mi) {
#pragma unroll
            for (int r = 0; r < 4; ++r) {
                int trow = tidl[rbase + mi * 16 + r];
                float rp = 0.f;
#pragma unroll
                for (int ni = 0; ni < 4; ++ni) {
                    float v = acc[mi][ni][r] + bv[ni];
                    v = fmaxf(v, 0.f);
                    rp += v * qpl[trow * 256 + cbase + ni * 16];
                }
                rp += __shfl_xor(rp, 1);
                rp += __shfl_xor(rp, 2);
                rp += __shfl_xor(rp, 4);
                rp += __shfl_xor(rp, 8);
                if (lr == 0)
                    spart[(((long long)g * Bn + orow0 + mi * 16 + r) << 3)
                          + (wc << 1) + bx] = rp;
            }
        }
    } else {
#pragma unroll
        for (int mi = 0; mi < 8; ++mi)
#pragma unroll
            for (int ni = 0; ni < 4; ++ni)
#pragma unroll
                for (int r = 0; r < 4; ++r) {
                    float v = acc[mi][ni][r] + bv[ni];
                    if (ACTF == 1) v = fmaxf(v, 0.f);
                    long long off = (long long)(orow0 + mi * 16 + r) * ldc + ocol0 + ni * 16;
                    if (OUTF == 0) Cf[off] = v;
                    else           Cb[off] = f2bf(v);
                }
    }
}

// ---------------- attn: scores from spart partials, softmax, weighted vals sum, loss ----------------
__global__ __launch_bounds__(256) void attn_kernel(
    const float* __restrict__ spart, const float* __restrict__ qb,
    const int* __restrict__ task_id, const unsigned short* __restrict__ vals,
    unsigned short* __restrict__ tower_in, float* __restrict__ loss_partial)
{
    int wv   = threadIdx.x >> 6;
    int lane = threadIdx.x & 63;
    int b    = blockIdx.x * 4 + wv;
    int t    = task_id[b];

    float s[E];
#pragma unroll
    for (int e = 0; e < E; ++e) {
        const float4* sp = (const float4*)(spart + (((long long)e * Bn + b) << 3));
        float4 p0 = sp[0], p1 = sp[1];
        s[e] = p0.x + p0.y + p0.z + p0.w + p1.x + p1.y + p1.z + p1.w + qb[e * NT + t];
    }

    float m = s[0];
#pragma unroll
    for (int e = 1; e < E; ++e) m = fmaxf(m, s[e]);
    float wgt[E];
    float sum = 0.f;
#pragma unroll
    for (int e = 0; e < E; ++e) { wgt[e] = expf(s[e] - m); sum += wgt[e]; }
    float inv = 1.f / sum;

    int d0 = lane * 4;
    float4 acc = make_float4(0.f, 0.f, 0.f, 0.f);
    float lb = 0.f;
#pragma unroll
    for (int e = 0; e < E; ++e) {
        float we = wgt[e] * inv;
        uint2 vv = *(const uint2*)&vals[((long long)e * Bn + b) * D + d0];
        acc.x += we * __uint_as_float(vv.x << 16);
        acc.y += we * __uint_as_float(vv.x & 0xffff0000u);
        acc.z += we * __uint_as_float(vv.y << 16);
        acc.w += we * __uint_as_float(vv.y & 0xffff0000u);
        lb += fminf(fmaxf(logf(we + 1e-10f), -6.f), 0.f);
    }
    ushort4 o;
    o.x = f2bf(acc.x); o.y = f2bf(acc.y); o.z = f2bf(acc.z); o.w = f2bf(acc.w);
    *(ushort4*)&tower_in[(long long)b * D + d0] = o;

    __shared__ float sm[4];
    if (lane == 0) sm[wv] = lb;
    __syncthreads();
    if (threadIdx.x == 0)
        loss_partial[blockIdx.x] = sm[0] + sm[1] + sm[2] + sm[3];
}

// ---------------- qfin: out[b] = sum(qpart[b][0..7])+tb3 ; last block: loss ----------------
__global__ __launch_bounds__(256) void qfin_kernel(
    const float* __restrict__ qpart, const float* __restrict__ tb3,
    float* __restrict__ out, const float* __restrict__ lossp)
{
    if (blockIdx.x == Bn / 256) {
        float s = 0.f;
        for (int i = threadIdx.x; i < Bn / 4; i += 256) s += lossp[i];
#pragma unroll
        for (int off = 32; off > 0; off >>= 1) s += __shfl_xor(s, off, 64);
        __shared__ float sm[4];
        if ((threadIdx.x & 63) == 0) sm[threadIdx.x >> 6] = s;
        __syncthreads();
        if (threadIdx.x == 0) out[Bn] = (-0.3f / Bn) * (sm[0] + sm[1] + sm[2] + sm[3]);
        return;
    }
    int b = blockIdx.x * 256 + threadIdx.x;
    const float4* qq = (const float4*)&qpart[b * 8];
    float4 a0 = qq[0], a1 = qq[1];
    out[b] = a0.x + a0.y + a0.z + a0.w + a1.x + a1.y + a1.z + a1.w + tb3[0];
}

extern "C" void kernel_launch(void* const* d_in, const int* in_sizes, int n_in,
                              void* d_out, int out_size, void* d_ws, size_t ws_size,
                              hipStream_t stream) {
    const float* state_feat = (const float*)d_in[0];
    const float* act        = (const float*)d_in[1];
    const int*   task_id    = (const int*)d_in[2];
    const float* rep_W1 = (const float*)d_in[3];
    const float* rep_b1 = (const float*)d_in[4];
    const float* rep_W2 = (const float*)d_in[5];
    const float* rep_b2 = (const float*)d_in[6];
    const float* emb    = (const float*)d_in[7];
    const float* kW1 = (const float*)d_in[8];
    const float* kb1 = (const float*)d_in[9];
    const float* kW2 = (const float*)d_in[10];
    const float* kb2 = (const float*)d_in[11];
    const float* vW1 = (const float*)d_in[12];
    const float* vb1 = (const float*)d_in[13];
    const float* vW2 = (const float*)d_in[14];
    const float* vb2 = (const float*)d_in[15];
    const float* tW1 = (const float*)d_in[16];
    const float* tb1 = (const float*)d_in[17];
    const float* tW2 = (const float*)d_in[18];
    const float* tb2 = (const float*)d_in[19];
    const float* tW3 = (const float*)d_in[20];
    const float* tb3 = (const float*)d_in[21];
    float* out = (float*)d_out;

    // ---- workspace (~92 MB) ----
    char* p = (char*)d_ws;
    auto alloc = [&](size_t bytes) {
        char* r = p;
        p += (bytes + 255) & ~(size_t)255;
        return r;
    };
    unsigned short* x      = (unsigned short*)alloc((size_t)Bn * KPAD * 2);
    unsigned short* repW1T = (unsigned short*)alloc((size_t)H1 * KPAD * 2);
    unsigned short* repW2T = (unsigned short*)alloc((size_t)H1 * H1 * 2);
    unsigned short* w1T    = (unsigned short*)alloc((size_t)2 * E * H2 * H1 * 2);  // K then V
    unsigned short* w2T    = (unsigned short*)alloc((size_t)E * D * H2 * 2);       // V only
    unsigned short* tW1T   = (unsigned short*)alloc((size_t)D * D * 2);
    unsigned short* tW2T   = (unsigned short*)alloc((size_t)D * D * 2);
    float*          b1cat  = (float*)alloc((size_t)2 * E * H2 * 4);
    float*          qp     = (float*)alloc((size_t)E * NT * H2 * 4);
    float*          qb     = (float*)alloc((size_t)E * NT * 4);
    char*           h1zone = alloc((size_t)Bn * H1 * 2);
    unsigned short* rep    = (unsigned short*)alloc((size_t)Bn * H1 * 2);
    unsigned short* hkv    = (unsigned short*)alloc((size_t)2 * E * Bn * H2 * 2);
    unsigned short* vals   = (unsigned short*)alloc((size_t)E * Bn * D * 2);
    float*          spart  = (float*)alloc((size_t)E * Bn * 8 * 4);
    float*          qpart  = (float*)alloc((size_t)Bn * 8 * 4);
    float*          lossp  = (float*)alloc((size_t)(Bn / 4) * 4);

    unsigned short* h1       = (unsigned short*)h1zone;
    unsigned short* tower_in = (unsigned short*)h1zone;
    unsigned short* t1       = (unsigned short*)(h1zone + (size_t)Bn * D * 2);
    unsigned short* hv = hkv + (size_t)E * Bn * H2;

    // ---- 1. prep_all: transposes + x-cast + qproj + bias concat (1 launch) ----
    TD2Arr da;
    int startAcc = 0;
    auto setd = [&](int i, const float* W, unsigned short* WT, int K, int Kpad, int N,
                    long long gsW, long long gsO, int groups) {
        TD2& dd = da.d[i];
        dd.W = W; dd.WT = WT; dd.K = K; dd.Kpad = Kpad; dd.N = N;
        dd.gsW = gsW; dd.gsO = gsO;
        dd.tilesN = N / 64;
        dd.perG = ((Kpad + 63) / 64) * dd.tilesN;
        dd.start = startAcc;
        startAcc += dd.perG * groups;
    };
    setd(0, rep_W1, repW1T, IN, KPAD, H1, 0, 0, 1);
    setd(1, rep_W2, repW2T, H1, H1, H1, 0, 0, 1);
    setd(2, kW1, w1T,                       H1, H1, H2, (long long)H1 * H2, (long long)H2 * H1, E);
    setd(3, vW1, w1T + (size_t)E * H2 * H1, H1, H1, H2, (long long)H1 * H2, (long long)H2 * H1, E);
    setd(4, vW2, w2T,                       H2, H2, D, (long long)H2 * D, (long long)D * H2, E);
    setd(5, tW1, tW1T, D, D, D, 0, 0, 1);
    setd(6, tW2, tW2T, D, D, D, 0, 0, 1);
    da.d[7] = da.d[6];
    da.d[7].start = 0x7fffffff;
    int totalBlocks = startAcc + PREPB + 17 + 32;
    prep_all<<<totalBlocks, 256, 0, stream>>>(
        da, startAcc, state_feat, act, x, kW2, kb2, emb, qp, qb, kb1, vb1, b1cat);

    // ---- 2. rep MLP (64x128-tile pipelined, XCD-swizzled) ----
    gemm64x128<KPAD, 1, 1><<<dim3(H1 / 128, Bn / 64, 1), 256, 0, stream>>>(
        x, repW1T, rep_b1, h1, H1, 0, 0, 0, 0);
    gemm64x128<H1, 0, 1><<<dim3(H1 / 128, Bn / 64, 1), 256, 0, stream>>>(
        h1, repW2T, rep_b2, rep, H1, 0, 0, 0, 0);

    // ---- 3. expert L1 K+V fused (256^2, scores in epilogue, XCD-swizzled); L2 V-only ----
    gemm256<H1, 1, 1, 1><<<dim3(H2 / 256, Bn / 256, 2 * E), 512, 0, stream>>>(
        rep, w1T, b1cat, hkv, H2,
        0, (long long)H2 * H1, H2, (long long)Bn * H2,
        task_id, qp, spart);
    gemm64x128<H2, 0, 1><<<dim3(D / 128, Bn / 64, E), 256, 0, stream>>>(
        hv, w2T, vb2, vals, D,
        (long long)Bn * H2, (long long)D * H2, D, (long long)Bn * D);

    // ---- 4. attention (scores from spart partials) ----
    attn_kernel<<<Bn / 4, 256, 0, stream>>>(
        spart, qb, task_id, vals, tower_in, lossp);

    // ---- 5. tower (64x128-tile; tower2 fuses the tW3 dot) ----
    gemm64x128<D, 1, 1><<<dim3(D / 128, Bn / 64, 1), 256, 0, stream>>>(
        tower_in, tW1T, tb1, t1, D, 0, 0, 0, 0);
    gemm64x128<D, 1, 2><<<dim3(D / 128, Bn / 64, 1), 256, 0, stream>>>(
        t1, tW2T, tb2, nullptr, D, 0, 0, 0, 0, tW3, qpart);

    // ---- 6. q + loss ----
    qfin_kernel<<<Bn / 256 + 1, 256, 0, stream>>>(qpart, tb3, out, lossp);
}

// Round 17
// 153.737 us; speedup vs baseline: 1.0632x; 1.0105x over previous
//
#include <hip/hip_runtime.h>

constexpr int Bn   = 4096;
constexpr int OBS  = 390;
constexpr int ACTN = 20;
constexpr int IN   = 410;   // OBS + ACTN
constexpr int KPAD = 448;   // IN padded to multiple of 64
constexpr int E    = 8;
constexpr int NT   = 10;
constexpr int H1   = 1024;
constexpr int H2   = 512;
constexpr int D    = 256;

typedef __bf16 bf16x8 __attribute__((ext_vector_type(8)));
typedef float  f32x4  __attribute__((ext_vector_type(4)));
typedef unsigned short u16x8 __attribute__((ext_vector_type(8)));

__device__ __forceinline__ unsigned short f2bf(float f) {
    unsigned int u = __float_as_uint(f);
    unsigned int r = u + 0x7fffu + ((u >> 16) & 1u);   // RNE
    return (unsigned short)(r >> 16);
}
__device__ __forceinline__ void gload16(void* lds_dst, const void* g_src) {
    __builtin_amdgcn_global_load_lds(
        (const __attribute__((address_space(1))) void*)g_src,
        (__attribute__((address_space(3))) void*)lds_dst,
        16, 0, 0);
}
// T1: bijective XCD-aware block remap (identity if nwg % 8 != 0) — gemm64x128 only
__device__ __forceinline__ void xcd_swz(int& bx, int& by, int& bz) {
    int nx = gridDim.x, ny = gridDim.y, nz = gridDim.z;
    int nwg = nx * ny * nz;
    int flat = blockIdx.x + nx * (blockIdx.y + ny * blockIdx.z);
    if ((nwg & 7) == 0) {
        int chunk = nwg >> 3;
        flat = (flat & 7) * chunk + (flat >> 3);
    }
    bx = flat % nx;
    int rest = flat / nx;
    by = rest % ny;
    bz = rest / ny;
}

// ---------------- prep_all: tc64 transposes + x-cast + qproj + bias concat, ONE launch ----------------
struct TD2 {
    const float* W;
    unsigned short* WT;
    int K, Kpad, N;
    long long gsW, gsO;
    int tilesN, perG, start;
};
struct TD2Arr { TD2 d[8]; };

constexpr int XCH    = KPAD / 8;            // 56 bf16x8 chunks per row
constexpr int PREPB  = (Bn * XCH) / 256;    // 896 blocks for x-cast

__global__ __launch_bounds__(256) void prep_all(
    TD2Arr da, int tcb,
    const float* __restrict__ sf, const float* __restrict__ ac,
    unsigned short* __restrict__ x,
    const float* __restrict__ kW2, const float* __restrict__ kb2,
    const float* __restrict__ emb, float* __restrict__ qp, float* __restrict__ qb,
    const float* __restrict__ kb1, const float* __restrict__ vb1,
    float* __restrict__ b1cat)
{
    __shared__ float tile[64][68];
    int bid = blockIdx.x;
    int t = threadIdx.x;

    if (bid < tcb) {
        int i = 0;
#pragma unroll
        for (int j = 1; j < 8; ++j) if (bid >= da.d[j].start) i = j;
        TD2 dd = da.d[i];
        int local = bid - dd.start;
        int g   = local / dd.perG;
        int rem = local - g * dd.perG;
        int kt  = rem / dd.tilesN;
        int nt  = rem - kt * dd.tilesN;
        const float* W = dd.W + (long long)g * dd.gsW;
        unsigned short* WT = dd.WT + (long long)g * dd.gsO;
        int k0 = kt * 64, n0 = nt * 64;
        {
            int kl  = t >> 4;
            int nl4 = (t & 15) * 4;
#pragma unroll
            for (int r = 0; r < 4; ++r) {
                int k = k0 + kl + r * 16;
                float4 v = make_float4(0.f, 0.f, 0.f, 0.f);
                if (k < dd.K) v = *(const float4*)(W + (long long)k * dd.N + n0 + nl4);
                *(float4*)&tile[kl + r * 16][nl4] = v;
            }
        }
        __syncthreads();
        int nl = t >> 2, kc = (t & 3) * 16;
        if (k0 + kc < dd.Kpad) {
            u16x8 o0, o1;
#pragma unroll
            for (int j = 0; j < 8; ++j) {
                o0[j] = f2bf(tile[kc + j][nl]);
                o1[j] = f2bf(tile[kc + 8 + j][nl]);
            }
            unsigned short* dst = WT + (long long)(n0 + nl) * dd.Kpad + k0 + kc;
            *(u16x8*)dst       = o0;
            *(u16x8*)(dst + 8) = o1;
        }
        return;
    }
    int bid2 = bid - tcb;
    if (bid2 < PREPB) {
        int cidx = bid2 * 256 + t;           // chunk index, 8 bf16 per chunk
        int b  = cidx / XCH;
        int cc = cidx - b * XCH;
        int k0 = cc * 8;
        u16x8 o;
        if (cc < 48) {                       // k0+7 <= 383 < OBS: pure state_feat
            const float* s = sf + (long long)b * OBS + k0;   // 8B-aligned
#pragma unroll
            for (int j = 0; j < 4; ++j) {
                float2 v = *(const float2*)(s + j * 2);
                o[j * 2]     = f2bf(v.x);
                o[j * 2 + 1] = f2bf(v.y);
            }
        } else {
#pragma unroll
            for (int j = 0; j < 8; ++j) {
                int k = k0 + j;
                float v = 0.f;
                if (k < OBS) v = sf[(long long)b * OBS + k];
                else if (k < IN) v = ac[b * ACTN + (k - OBS)];
                o[j] = f2bf(v);
            }
        }
        *(u16x8*)(x + (long long)b * KPAD + k0) = o;
        return;
    }
    if (bid2 < PREPB + 17) {
        int qbid = bid2 - PREPB;
        float* tq = &tile[0][0];   // [NT*D] = 2560 floats fits
        for (int i = t; i < NT * D; i += 256) tq[i] = tanhf(emb[i]);
        __syncthreads();
        if (qbid < 16) {
            int e = qbid >> 1;
            int h = (qbid & 1) * 256 + t;
            const float4* row = (const float4*)(kW2 + ((long long)e * H2 + h) * D);
            float acc[NT] = {};
            for (int d4 = 0; d4 < D / 4; ++d4) {
                float4 wv = row[d4];
#pragma unroll
                for (int tt = 0; tt < NT; ++tt)
                    acc[tt] += wv.x * tq[tt * D + d4 * 4] + wv.y * tq[tt * D + d4 * 4 + 1]
                             + wv.z * tq[tt * D + d4 * 4 + 2] + wv.w * tq[tt * D + d4 * 4 + 3];
            }
#pragma unroll
            for (int tt = 0; tt < NT; ++tt)
                qp[((long long)e * NT + tt) * H2 + h] = acc[tt];
        } else if (t < E * NT) {
            int e = t / NT, tt = t - e * NT;
            float s = 0.f;
            for (int d = 0; d < D; ++d) s += kb2[e * D + d] * tq[tt * D + d];
            qb[e * NT + tt] = s;
        }
        return;
    }
    int i = (bid2 - PREPB - 17) * 256 + t;   // < 2*E*H2 = 8192
    b1cat[i] = (i < E * H2) ? kb1[i] : vb1[i - E * H2];
}

// ---------------- 64x128 pipelined bf16 GEMM (R12 2-phase, BK=64) + T1 swizzle ----------------
// 4 waves side-by-side in N (each 64M x 32N, acc[4][2]). Grid (N/128, M/64, groups).
// OUTF: 0=f32 C, 1=bf16 C, 2=no C store, per-row tW3 dot -> qpart[row][bx*4+w]
template <int KT, int ACTF, int OUTF>
__global__ __launch_bounds__(256, 3) void gemm64x128(
    const unsigned short* __restrict__ A, const unsigned short* __restrict__ BT,
    const float* __restrict__ bias, void* __restrict__ Cout,
    int ldc, long long gsA, long long gsBT, long long gsBias, long long gsC,
    const float* __restrict__ tW3 = nullptr, float* __restrict__ qpart = nullptr)
{
    constexpr int NTK = KT / 64;
    static_assert(NTK >= 2, "KT must be >= 128");

    int bx, by, bz;
    xcd_swz(bx, by, bz);
    const int g = bz;
    A    += (long long)g * gsA;
    BT   += (long long)g * gsBT;
    bias += (long long)g * gsBias;
    float*          Cf = (float*)Cout + (long long)g * gsC;
    unsigned short* Cb = (unsigned short*)Cout + (long long)g * gsC;

    __shared__ __align__(16) char smem[49152];
    const int tid = threadIdx.x;
    const int l  = tid & 63, lr = l & 15, lk = l >> 4;
    const int w  = tid >> 6;
    const int gm = by * 64, gn = bx * 128;

    const int srow = tid >> 3;                    // 0..31
    const int cg   = (tid & 7) ^ (srow & 7);      // pre-swizzled global chunk
    const unsigned short* gA = A  + (long long)(gm + srow) * KT + cg * 8;
    const unsigned short* gB = BT + (long long)(gn + srow) * KT + cg * 8;
    const int wb = w * 1024;

    const int cs0 = ((0 | lk) ^ (lr & 7)) * 16;
    const int cs1 = ((4 | lk) ^ (lr & 7)) * 16;
    const int aRow = lr * 128;
    const int bRow = 8192 + (w * 32 + lr) * 128;

    f32x4 acc[4][2] = {};

    auto stA = [&](int c, int kt) {
#pragma unroll
        for (int j = 0; j < 2; ++j)
            gload16(smem + c * 24576 + j * 4096 + wb,
                    gA + (long long)(j * 32) * KT + kt * 64);
    };
    auto stB = [&](int c, int kt) {
#pragma unroll
        for (int j = 0; j < 4; ++j)
            gload16(smem + c * 24576 + 8192 + j * 4096 + wb,
                    gB + (long long)(j * 32) * KT + kt * 64);
    };

    // prologue: A(0)=2, B(0)=4, A(1)=2; vmcnt(2) retires tile0's 6, keeps A(1)
    stA(0, 0); stB(0, 0); stA(1, 1);
    asm volatile("s_waitcnt vmcnt(2)" ::: "memory");
    __builtin_amdgcn_s_barrier();
    __builtin_amdgcn_sched_barrier(0);

#pragma unroll
    for (int kt = 0; kt < NTK; ++kt) {
        const int c = kt & 1;
        const char* bufc = smem + c * 24576;
        bf16x8 a[4][2], b[1][2], b2[1][2];

        // ph0: read A-all + b(nf0); stage B(kt+1) -> buf c^1; 8 MFMA
#pragma unroll
        for (int m = 0; m < 4; ++m) {
            const char* base = bufc + aRow + m * 2048;
            a[m][0] = *(const bf16x8*)(base + cs0);
            a[m][1] = *(const bf16x8*)(base + cs1);
        }
        {
            const char* base = bufc + bRow;
            b[0][0] = *(const bf16x8*)(base + cs0);
            b[0][1] = *(const bf16x8*)(base + cs1);
        }
        if (kt + 1 < NTK) stB(c ^ 1, kt + 1);
        __builtin_amdgcn_s_setprio(1);
#pragma unroll
        for (int ks = 0; ks < 2; ++ks)
#pragma unroll
            for (int m = 0; m < 4; ++m)
                acc[m][0] = __builtin_amdgcn_mfma_f32_16x16x32_bf16(
                    a[m][ks], b[0][ks], acc[m][0], 0, 0, 0);
        __builtin_amdgcn_s_setprio(0);

        // ph1: read b(nf1); free buf c; stage A(kt+2) -> buf c; 8 MFMA
        {
            const char* base = bufc + bRow + 2048;
            b2[0][0] = *(const bf16x8*)(base + cs0);
            b2[0][1] = *(const bf16x8*)(base + cs1);
        }
        asm volatile("s_waitcnt lgkmcnt(0)" ::: "memory");
        __builtin_amdgcn_sched_barrier(0);
        if (kt + 2 < NTK) {
            __builtin_amdgcn_s_barrier();
            __builtin_amdgcn_sched_barrier(0);
            stA(c, kt + 2);
        }
        __builtin_amdgcn_s_setprio(1);
#pragma unroll
        for (int ks = 0; ks < 2; ++ks)
#pragma unroll
            for (int m = 0; m < 4; ++m)
                acc[m][1] = __builtin_amdgcn_mfma_f32_16x16x32_bf16(
                    a[m][ks], b2[0][ks], acc[m][1], 0, 0, 0);
        __builtin_amdgcn_s_setprio(0);

        // boundary: tile kt+1 (A=2,B=4) landed; A(kt+2)=2 in flight
        if (kt + 1 < NTK) {
            if (kt + 2 < NTK) { asm volatile("s_waitcnt vmcnt(2)" ::: "memory"); }
            else              { asm volatile("s_waitcnt vmcnt(0)" ::: "memory"); }
            __builtin_amdgcn_sched_barrier(0);
            __builtin_amdgcn_s_barrier();
            __builtin_amdgcn_sched_barrier(0);
        }
    }

    const int orow0 = gm + lk * 4;
    const int ocol0 = gn + w * 32 + lr;
    float bv[2];
#pragma unroll
    for (int nf = 0; nf < 2; ++nf) bv[nf] = bias[gn + w * 32 + lr + nf * 16];

    if (OUTF == 2) {
        float tw3v[2];
#pragma unroll
        for (int nf = 0; nf < 2; ++nf) tw3v[nf] = tW3[gn + w * 32 + lr + nf * 16];
#pragma unroll
        for (int mi = 0; mi < 4; ++mi)
#pragma unroll
            for (int r = 0; r < 4; ++r) {
                float part = 0.f;
#pragma unroll
                for (int nf = 0; nf < 2; ++nf) {
                    float v = acc[mi][nf][r] + bv[nf];
                    if (ACTF == 1) v = fmaxf(v, 0.f);
                    part += v * tw3v[nf];
                }
                part += __shfl_xor(part, 1);
                part += __shfl_xor(part, 2);
                part += __shfl_xor(part, 4);
                part += __shfl_xor(part, 8);
                if (lr == 0)
                    qpart[(orow0 + mi * 16 + r) * 8 + bx * 4 + w] = part;
            }
    } else {
#pragma unroll
        for (int mi = 0; mi < 4; ++mi)
#pragma unroll
            for (int nf = 0; nf < 2; ++nf)
#pragma unroll
                for (int r = 0; r < 4; ++r) {
                    float v = acc[mi][nf][r] + bv[nf];
                    if (ACTF == 1) v = fmaxf(v, 0.f);
                    long long off = (long long)(orow0 + mi * 16 + r) * ldc + ocol0 + nf * 16;
                    if (OUTF == 0) Cf[off] = v;
                    else           Cb[off] = f2bf(v);
                }
    }
}

// ---------------- 256x256 8-wave pipelined bf16 GEMM (R12-proven 2-phase, NO swizzle) ----------------
// SC=1: groups g<E score-only; qp slice + task_id staged into the idle LDS buffer
// DURING the last K-tile (buffer c^1 proven drained by the preceding boundary).
template <int KTOT, int ACTF, int OUTF, int SC>
__global__ __launch_bounds__(512, 2) void gemm256(
    const unsigned short* __restrict__ A, const unsigned short* __restrict__ BT,
    const float* __restrict__ bias, void* __restrict__ Cout,
    int ldc, long long gsA, long long gsBT, long long gsBias, long long gsC,
    const int* __restrict__ task_id, const float* __restrict__ qp,
    float* __restrict__ spart)
{
    constexpr int NT_ = KTOT / 64;
    static_assert(NT_ >= 4 && (NT_ % 2) == 0, "KTOT must be multiple of 128");
    constexpr int QBUF = (((NT_ - 1) & 1) ^ 1) * 65536;   // idle buffer during last tile

    const int g = blockIdx.z;
    A    += (long long)g * gsA;
    BT   += (long long)g * gsBT;
    bias += (long long)g * gsBias;
    float*          Cf = (float*)Cout + (long long)g * gsC;
    unsigned short* Cb = (unsigned short*)Cout + (long long)g * gsC;

    __shared__ __align__(16) char smem[131072];

    const int tid = threadIdx.x;
    const int l  = tid & 63;
    const int lr = l & 15, lk = l >> 4;
    const int w  = tid >> 6;
    const int wr = w >> 2, wc = w & 3;
    const int gm = blockIdx.y * 256, gn = blockIdx.x * 256;

    const int srow = tid >> 3;
    const int cg   = (tid & 7) ^ (srow & 7);
    const unsigned short* gA = A  + (long long)(gm + srow) * KTOT + cg * 8;
    const unsigned short* gB = BT + (long long)(gn + srow) * KTOT + cg * 8;
    const int wbase = (tid & ~63) * 16;

    const int cs0 = ((0 | lk) ^ (lr & 7)) * 16;
    const int cs1 = ((4 | lk) ^ (lr & 7)) * 16;
    const int aRow = wr * 16384 + lr * 128;
    const int bRow = 32768 + (wc >> 1) * 16384 + ((wc & 1) * 64 + lr) * 128;

    f32x4 acc[8][4] = {};

    auto stA = [&](int c, int s, int kt) {
        const unsigned short* src = gA + (long long)(s * 128) * KTOT + kt * 64;
        char* d = smem + c * 65536 + s * 16384 + wbase;
        gload16(d,        src);
        gload16(d + 8192, src + (long long)64 * KTOT);
    };
    auto stB = [&](int c, int s, int kt) {
        const unsigned short* src = gB + (long long)(s * 128) * KTOT + kt * 64;
        char* d = smem + c * 65536 + 32768 + s * 16384 + wbase;
        gload16(d,        src);
        gload16(d + 8192, src + (long long)64 * KTOT);
    };

    stA(0, 0, 0); stA(0, 1, 0); stB(0, 0, 0); stB(0, 1, 0);
    stA(1, 0, 1); stA(1, 1, 1);
    asm volatile("s_waitcnt vmcnt(4)" ::: "memory");
    __builtin_amdgcn_s_barrier();
    __builtin_amdgcn_sched_barrier(0);

#pragma unroll
    for (int kt = 0; kt < NT_; ++kt) {
        const int c = kt & 1;
        const char* bufc = smem + c * 65536;
        bf16x8 a0[4], a1[4], b0[4], b1[4];

        // last tile: overlap SC-epilogue staging into the idle buffer (c^1)
        if (SC && kt == NT_ - 1 && g < E) {
            float* qpl  = (float*)(smem + QBUF);
            int*   tidl = (int*)(smem + QBUF + NT * 256 * 4);
            for (int i = tid; i < NT * 256; i += 512) {
                int tt = i >> 8, cc = i & 255;
                qpl[i] = qp[((long long)(g * NT + tt)) * H2 + gn + cc];
            }
            if (tid < 256) tidl[tid] = task_id[gm + tid];
        }

        // ---- ph0: read A-half0 + all B; issue next-tile B staging ----
#pragma unroll
        for (int m = 0; m < 4; ++m) {
            const char* base = bufc + aRow + m * (16 * 128);
            a0[m] = *(const bf16x8*)(base + cs0);
            a1[m] = *(const bf16x8*)(base + cs1);
        }
#pragma unroll
        for (int n = 0; n < 4; ++n) {
            const char* base = bufc + bRow + n * (16 * 128);
            b0[n] = *(const bf16x8*)(base + cs0);
            b1[n] = *(const bf16x8*)(base + cs1);
        }
        if (kt + 1 < NT_) { stB(c ^ 1, 0, kt + 1); stB(c ^ 1, 1, kt + 1); }
        __builtin_amdgcn_s_setprio(1);
#pragma unroll
        for (int m = 0; m < 4; ++m)
#pragma unroll
            for (int n = 0; n < 4; ++n) {
                acc[m][n] = __builtin_amdgcn_mfma_f32_16x16x32_bf16(a0[m], b0[n], acc[m][n], 0, 0, 0);
                acc[m][n] = __builtin_amdgcn_mfma_f32_16x16x32_bf16(a1[m], b1[n], acc[m][n], 0, 0, 0);
            }
        __builtin_amdgcn_s_setprio(0);

        // ---- ph1: read A-half1; free buffer; stage tile t+2 A-units ----
#pragma unroll
        for (int m = 0; m < 4; ++m) {
            const char* base = bufc + aRow + (64 + m * 16) * 128;
            a0[m] = *(const bf16x8*)(base + cs0);
            a1[m] = *(const bf16x8*)(base + cs1);
        }
        asm volatile("s_waitcnt lgkmcnt(0)" ::: "memory");
        __builtin_amdgcn_sched_barrier(0);
        if (kt + 2 < NT_) {
            __builtin_amdgcn_s_barrier();
            __builtin_amdgcn_sched_barrier(0);
            stA(c, 0, kt + 2); stA(c, 1, kt + 2);
        }
        __builtin_amdgcn_s_setprio(1);
#pragma unroll
        for (int m = 0; m < 4; ++m)
#pragma unroll
            for (int n = 0; n < 4; ++n) {
                acc[4 + m][n] = __builtin_amdgcn_mfma_f32_16x16x32_bf16(a0[m], b0[n], acc[4 + m][n], 0, 0, 0);
                acc[4 + m][n] = __builtin_amdgcn_mfma_f32_16x16x32_bf16(a1[m], b1[n], acc[4 + m][n], 0, 0, 0);
            }
        __builtin_amdgcn_s_setprio(0);

        if (kt + 1 < NT_) {
            if (kt + 2 < NT_) { asm volatile("s_waitcnt vmcnt(4)" ::: "memory"); }
            else              { asm volatile("s_waitcnt vmcnt(0)" ::: "memory"); }
            __builtin_amdgcn_sched_barrier(0);
            __builtin_amdgcn_s_barrier();
            __builtin_amdgcn_sched_barrier(0);
        }
    }

    const int orow0 = gm + wr * 128 + lk * 4;
    const int ocol0 = gn + wc * 64 + lr;
    float bv[4];
#pragma unroll
    for (int ni = 0; ni < 4; ++ni) bv[ni] = bias[gn + wc * 64 + lr + ni * 16];

    if (SC && g < E) {
        __syncthreads();                       // staging writes visible to all waves
        const float* qpl  = (const float*)(smem + QBUF);
        const int*   tidl = (const int*)(smem + QBUF + NT * 256 * 4);

        const int rbase = wr * 128 + lk * 4;
        const int cbase = wc * 64 + lr;
#pragma unroll
        for (int mi = 0; mi < 8; ++mi) {
#pragma unroll
            for (int r = 0; r < 4; ++r) {
                int trow = tidl[rbase + mi * 16 + r];
                float rp = 0.f;
#pragma unroll
                for (int ni = 0; ni < 4; ++ni) {
                    float v = acc[mi][ni][r] + bv[ni];
                    v = fmaxf(v, 0.f);
                    rp += v * qpl[trow * 256 + cbase + ni * 16];
                }
                rp += __shfl_xor(rp, 1);
                rp += __shfl_xor(rp, 2);
                rp += __shfl_xor(rp, 4);
                rp += __shfl_xor(rp, 8);
                if (lr == 0)
                    spart[(((long long)g * Bn + orow0 + mi * 16 + r) << 3)
                          + (wc << 1) + blockIdx.x] = rp;
            }
        }
    } else {
#pragma unroll
        for (int mi = 0; mi < 8; ++mi)
#pragma unroll
            for (int ni = 0; ni < 4; ++ni)
#pragma unroll
                for (int r = 0; r < 4; ++r) {
                    float v = acc[mi][ni][r] + bv[ni];
                    if (ACTF == 1) v = fmaxf(v, 0.f);
                    long long off = (long long)(orow0 + mi * 16 + r) * ldc + ocol0 + ni * 16;
                    if (OUTF == 0) Cf[off] = v;
                    else           Cb[off] = f2bf(v);
                }
    }
}

// ---------------- attn: scores from spart partials, softmax, weighted vals sum, loss ----------------
__global__ __launch_bounds__(256) void attn_kernel(
    const float* __restrict__ spart, const float* __restrict__ qb,
    const int* __restrict__ task_id, const unsigned short* __restrict__ vals,
    unsigned short* __restrict__ tower_in, float* __restrict__ loss_partial)
{
    int wv   = threadIdx.x >> 6;
    int lane = threadIdx.x & 63;
    int b    = blockIdx.x * 4 + wv;
    int t    = task_id[b];

    float s[E];
#pragma unroll
    for (int e = 0; e < E; ++e) {
        const float4* sp = (const float4*)(spart + (((long long)e * Bn + b) << 3));
        float4 p0 = sp[0], p1 = sp[1];
        s[e] = p0.x + p0.y + p0.z + p0.w + p1.x + p1.y + p1.z + p1.w + qb[e * NT + t];
    }

    float m = s[0];
#pragma unroll
    for (int e = 1; e < E; ++e) m = fmaxf(m, s[e]);
    float wgt[E];
    float sum = 0.f;
#pragma unroll
    for (int e = 0; e < E; ++e) { wgt[e] = expf(s[e] - m); sum += wgt[e]; }
    float inv = 1.f / sum;

    int d0 = lane * 4;
    float4 acc = make_float4(0.f, 0.f, 0.f, 0.f);
    float lb = 0.f;
#pragma unroll
    for (int e = 0; e < E; ++e) {
        float we = wgt[e] * inv;
        uint2 vv = *(const uint2*)&vals[((long long)e * Bn + b) * D + d0];
        acc.x += we * __uint_as_float(vv.x << 16);
        acc.y += we * __uint_as_float(vv.x & 0xffff0000u);
        acc.z += we * __uint_as_float(vv.y << 16);
        acc.w += we * __uint_as_float(vv.y & 0xffff0000u);
        lb += fminf(fmaxf(logf(we + 1e-10f), -6.f), 0.f);
    }
    ushort4 o;
    o.x = f2bf(acc.x); o.y = f2bf(acc.y); o.z = f2bf(acc.z); o.w = f2bf(acc.w);
    *(ushort4*)&tower_in[(long long)b * D + d0] = o;

    __shared__ float sm[4];
    if (lane == 0) sm[wv] = lb;
    __syncthreads();
    if (threadIdx.x == 0)
        loss_partial[blockIdx.x] = sm[0] + sm[1] + sm[2] + sm[3];
}

// ---------------- qfin: out[b] = sum(qpart[b][0..7])+tb3 ; last block: loss ----------------
__global__ __launch_bounds__(256) void qfin_kernel(
    const float* __restrict__ qpart, const float* __restrict__ tb3,
    float* __restrict__ out, const float* __restrict__ lossp)
{
    if (blockIdx.x == Bn / 256) {
        float s = 0.f;
        for (int i = threadIdx.x; i < Bn / 4; i += 256) s += lossp[i];
#pragma unroll
        for (int off = 32; off > 0; off >>= 1) s += __shfl_xor(s, off, 64);
        __shared__ float sm[4];
        if ((threadIdx.x & 63) == 0) sm[threadIdx.x >> 6] = s;
        __syncthreads();
        if (threadIdx.x == 0) out[Bn] = (-0.3f / Bn) * (sm[0] + sm[1] + sm[2] + sm[3]);
        return;
    }
    int b = blockIdx.x * 256 + threadIdx.x;
    const float4* qq = (const float4*)&qpart[b * 8];
    float4 a0 = qq[0], a1 = qq[1];
    out[b] = a0.x + a0.y + a0.z + a0.w + a1.x + a1.y + a1.z + a1.w + tb3[0];
}

extern "C" void kernel_launch(void* const* d_in, const int* in_sizes, int n_in,
                              void* d_out, int out_size, void* d_ws, size_t ws_size,
                              hipStream_t stream) {
    const float* state_feat = (const float*)d_in[0];
    const float* act        = (const float*)d_in[1];
    const int*   task_id    = (const int*)d_in[2];
    const float* rep_W1 = (const float*)d_in[3];
    const float* rep_b1 = (const float*)d_in[4];
    const float* rep_W2 = (const float*)d_in[5];
    const float* rep_b2 = (const float*)d_in[6];
    const float* emb    = (const float*)d_in[7];
    const float* kW1 = (const float*)d_in[8];
    const float* kb1 = (const float*)d_in[9];
    const float* kW2 = (const float*)d_in[10];
    const float* kb2 = (const float*)d_in[11];
    const float* vW1 = (const float*)d_in[12];
    const float* vb1 = (const float*)d_in[13];
    const float* vW2 = (const float*)d_in[14];
    const float* vb2 = (const float*)d_in[15];
    const float* tW1 = (const float*)d_in[16];
    const float* tb1 = (const float*)d_in[17];
    const float* tW2 = (const float*)d_in[18];
    const float* tb2 = (const float*)d_in[19];
    const float* tW3 = (const float*)d_in[20];
    const float* tb3 = (const float*)d_in[21];
    float* out = (float*)d_out;

    // ---- workspace (~92 MB) ----
    char* p = (char*)d_ws;
    auto alloc = [&](size_t bytes) {
        char* r = p;
        p += (bytes + 255) & ~(size_t)255;
        return r;
    };
    unsigned short* x      = (unsigned short*)alloc((size_t)Bn * KPAD * 2);
    unsigned short* repW1T = (unsigned short*)alloc((size_t)H1 * KPAD * 2);
    unsigned short* repW2T = (unsigned short*)alloc((size_t)H1 * H1 * 2);
    unsigned short* w1T    = (unsigned short*)alloc((size_t)2 * E * H2 * H1 * 2);  // K then V
    unsigned short* w2T    = (unsigned short*)alloc((size_t)E * D * H2 * 2);       // V only
    unsigned short* tW1T   = (unsigned short*)alloc((size_t)D * D * 2);
    unsigned short* tW2T   = (unsigned short*)alloc((size_t)D * D * 2);
    float*          b1cat  = (float*)alloc((size_t)2 * E * H2 * 4);
    float*          qp     = (float*)alloc((size_t)E * NT * H2 * 4);
    float*          qb     = (float*)alloc((size_t)E * NT * 4);
    char*           h1zone = alloc((size_t)Bn * H1 * 2);
    unsigned short* rep    = (unsigned short*)alloc((size_t)Bn * H1 * 2);
    unsigned short* hkv    = (unsigned short*)alloc((size_t)2 * E * Bn * H2 * 2);
    unsigned short* vals   = (unsigned short*)alloc((size_t)E * Bn * D * 2);
    float*          spart  = (float*)alloc((size_t)E * Bn * 8 * 4);
    float*          qpart  = (float*)alloc((size_t)Bn * 8 * 4);
    float*          lossp  = (float*)alloc((size_t)(Bn / 4) * 4);

    unsigned short* h1       = (unsigned short*)h1zone;
    unsigned short* tower_in = (unsigned short*)h1zone;
    unsigned short* t1       = (unsigned short*)(h1zone + (size_t)Bn * D * 2);
    unsigned short* hv = hkv + (size_t)E * Bn * H2;

    // ---- 1. prep_all: transposes + x-cast + qproj + bias concat (1 launch) ----
    TD2Arr da;
    int startAcc = 0;
    auto setd = [&](int i, const float* W, unsigned short* WT, int K, int Kpad, int N,
                    long long gsW, long long gsO, int groups) {
        TD2& dd = da.d[i];
        dd.W = W; dd.WT = WT; dd.K = K; dd.Kpad = Kpad; dd.N = N;
        dd.gsW = gsW; dd.gsO = gsO;
        dd.tilesN = N / 64;
        dd.perG = ((Kpad + 63) / 64) * dd.tilesN;
        dd.start = startAcc;
        startAcc += dd.perG * groups;
    };
    setd(0, rep_W1, repW1T, IN, KPAD, H1, 0, 0, 1);
    setd(1, rep_W2, repW2T, H1, H1, H1, 0, 0, 1);
    setd(2, kW1, w1T,                       H1, H1, H2, (long long)H1 * H2, (long long)H2 * H1, E);
    setd(3, vW1, w1T + (size_t)E * H2 * H1, H1, H1, H2, (long long)H1 * H2, (long long)H2 * H1, E);
    setd(4, vW2, w2T,                       H2, H2, D, (long long)H2 * D, (long long)D * H2, E);
    setd(5, tW1, tW1T, D, D, D, 0, 0, 1);
    setd(6, tW2, tW2T, D, D, D, 0, 0, 1);
    da.d[7] = da.d[6];
    da.d[7].start = 0x7fffffff;
    int totalBlocks = startAcc + PREPB + 17 + 32;
    prep_all<<<totalBlocks, 256, 0, stream>>>(
        da, startAcc, state_feat, act, x, kW2, kb2, emb, qp, qb, kb1, vb1, b1cat);

    // ---- 2. rep MLP (64x128-tile pipelined, XCD-swizzled) ----
    gemm64x128<KPAD, 1, 1><<<dim3(H1 / 128, Bn / 64, 1), 256, 0, stream>>>(
        x, repW1T, rep_b1, h1, H1, 0, 0, 0, 0);
    gemm64x128<H1, 0, 1><<<dim3(H1 / 128, Bn / 64, 1), 256, 0, stream>>>(
        h1, repW2T, rep_b2, rep, H1, 0, 0, 0, 0);

    // ---- 3. expert L1 K+V fused (256^2, scores in epilogue, no swizzle); L2 V-only ----
    gemm256<H1, 1, 1, 1><<<dim3(H2 / 256, Bn / 256, 2 * E), 512, 0, stream>>>(
        rep, w1T, b1cat, hkv, H2,
        0, (long long)H2 * H1, H2, (long long)Bn * H2,
        task_id, qp, spart);
    gemm64x128<H2, 0, 1><<<dim3(D / 128, Bn / 64, E), 256, 0, stream>>>(
        hv, w2T, vb2, vals, D,
        (long long)Bn * H2, (long long)D * H2, D, (long long)Bn * D);

    // ---- 4. attention (scores from spart partials) ----
    attn_kernel<<<Bn / 4, 256, 0, stream>>>(
        spart, qb, task_id, vals, tower_in, lossp);

    // ---- 5. tower (64x128-tile; tower2 fuses the tW3 dot) ----
    gemm64x128<D, 1, 1><<<dim3(D / 128, Bn / 64, 1), 256, 0, stream>>>(
        tower_in, tW1T, tb1, t1, D, 0, 0, 0, 0);
    gemm64x128<D, 1, 2><<<dim3(D / 128, Bn / 64, 1), 256, 0, stream>>>(
        t1, tW2T, tb2, nullptr, D, 0, 0, 0, 0, tW3, qpart);

    // ---- 6. q + loss ----
    qfin_kernel<<<Bn / 256 + 1, 256, 0, stream>>>(qpart, tb3, out, lossp);
}